// Round 12
// baseline (535.409 us; speedup 1.0000x reference)
//
#include <hip/hip_runtime.h>
#include <hip/hip_bf16.h>

typedef unsigned short u16;
typedef __attribute__((ext_vector_type(8))) short bf16x8;
typedef __attribute__((ext_vector_type(4))) float f32x4;

#define FINF __builtin_huge_valf()

static __device__ __forceinline__ float bf2f(u16 v){ union{unsigned u; float f;} c; c.u = ((unsigned)v)<<16; return c.f; }
static __device__ __forceinline__ u16 f2bf(float f){ union{__hip_bfloat16 h; u16 u;} c; c.h = __float2bfloat16(f); return c.u; }
static __device__ __forceinline__ bf16x8 scale8(bf16x8 v, float s){
  bf16x8 o;
  #pragma unroll
  for (int e=0;e<8;e++) o[e] = (short)f2bf(bf2f((u16)v[e])*s);
  return o;
}

// async global->LDS, 16B per lane; LDS dest = wave-uniform base + lane*16
static __device__ __forceinline__ void gload16(const void* g, void* l){
  __builtin_amdgcn_global_load_lds(
      (const __attribute__((address_space(1))) void*)g,
      (__attribute__((address_space(3))) void*)l, 16, 0, 0);
}

// raw-barrier pipeline primitives (rule #18)
#define WAIT_VM0()   { asm volatile("s_waitcnt vmcnt(0)" ::: "memory"); __builtin_amdgcn_sched_barrier(0); }
#define WAIT_ALL0()  { asm volatile("s_waitcnt vmcnt(0) lgkmcnt(0)" ::: "memory"); __builtin_amdgcn_sched_barrier(0); }
#define BARRIER()    { __builtin_amdgcn_sched_barrier(0); __builtin_amdgcn_s_barrier(); __builtin_amdgcn_sched_barrier(0); }

// ---------------------------------------------------------------- cvt
struct CvtArgs {
  const float* src[14];
  u16* dst[14];
  int n[14];
};
__global__ __launch_bounds__(256) void cvt_multi(CvtArgs a){
  int seg = blockIdx.y;
  const float* s = a.src[seg]; u16* d = a.dst[seg]; int n = a.n[seg];
  for (int i = (blockIdx.x*256 + threadIdx.x)*4; i < n; i += gridDim.x*256*4){
    float4 v = *(const float4*)(s + i);
    ushort4 o = { f2bf(v.x), f2bf(v.y), f2bf(v.z), f2bf(v.w) };
    *(ushort4*)(d + i) = o;
  }
}

__global__ __launch_bounds__(256) void concat_bias(const float* a, const float* b, const float* c, float* o){
  int i = blockIdx.x*256 + threadIdx.x;   // 1536
  o[i] = i < 512 ? a[i] : (i < 1024 ? b[i-512] : c[i-1024]);
}

// ---------------------------------------------------------------- GEMM  C = A @ B^T (+bias, epilogues)
// (round-9 config: 2-buffer, vmcnt(0)+barrier — measured best)
// EPI: 0=f32, 1=bf16, 2=f32+residual, 3=qgelu bf16, 4=sim, 5=perm f32,
//      6=residual+out-permute, 7=f32 + glob side-write (l==0 rows)
template<int BM, int EPI, int MW>
__global__ __launch_bounds__(256,MW) void gemm_nt(
    const u16* __restrict__ A, const u16* __restrict__ Bw,
    const float* __restrict__ bias, const float* aux, void* out,
    int M, int Nn, int K, int ldc, long aBatch, long bBatch, long cBatch)
{
  constexpr int MI = BM/32;
  constexpr int WSPAN = BM/2;
  __shared__ __align__(16) u16 a_lds[2*BM*64];
  __shared__ __align__(16) u16 b_lds[2*128*64];
  const int z = blockIdx.z;
  const u16* Az = A + (long)z*aBatch;
  const u16* Bz = Bw + (long)z*bBatch;
  const int n0 = blockIdx.x*128, m0 = blockIdx.y*BM;
  const int t = threadIdx.x, lane = t & 63, wave = t >> 6;
  const int wr = wave >> 1, wc = wave & 1;
  const int r = lane & 15, kq = lane >> 4;

  const int srow = t >> 3;                        // 0..31
  const int scol = ((t&7)*8) ^ ((srow&7)<<3);     // swizzled source col (u16)
  int rowA[MI], rowB[4];
  #pragma unroll
  for (int i=0;i<MI;i++){ int ga = m0 + i*32 + srow; rowA[i] = ga < M ? ga : M-1; }
  #pragma unroll
  for (int i=0;i<4;i++){ int gb = n0 + i*32 + srow; rowB[i] = gb < Nn ? gb : Nn-1; }

  f32x4 acc[MI][4] = {};
  const int nkt = K >> 6;

  auto STAGE = [&](int kt, int buf){
    const long koff = (long)kt*64 + scol;
    #pragma unroll
    for (int i=0;i<MI;i++)
      gload16(Az + (long)rowA[i]*K + koff, (char*)a_lds + buf*(BM*128) + i*4096 + wave*1024);
    #pragma unroll
    for (int i=0;i<4;i++)
      gload16(Bz + (long)rowB[i]*K + koff, (char*)b_lds + buf*16384 + i*4096 + wave*1024);
  };

  STAGE(0,0);
  WAIT_VM0(); BARRIER();
  for (int kt=0; kt<nkt; kt++){
    const int cur = kt&1;
    if (kt+1 < nkt) STAGE(kt+1, cur^1);
    const u16* al = a_lds + cur*BM*64;
    const u16* bl = b_lds + cur*8192;
    #pragma unroll
    for (int kk=0; kk<2; kk++){
      bf16x8 af[MI], bfr[4];
      #pragma unroll
      for (int i=0;i<MI;i++){
        int rw = wr*WSPAN + i*16 + r;
        af[i] = *(const bf16x8*)&al[rw*64 + ((kk*32 + kq*8) ^ ((rw&7)<<3))];
      }
      #pragma unroll
      for (int j=0;j<4;j++){
        int rw = wc*64 + j*16 + r;
        bfr[j] = *(const bf16x8*)&bl[rw*64 + ((kk*32 + kq*8) ^ ((rw&7)<<3))];
      }
      #pragma unroll
      for (int i=0;i<MI;i++)
        #pragma unroll
        for (int j=0;j<4;j++)
          acc[i][j] = __builtin_amdgcn_mfma_f32_16x16x32_bf16(af[i], bfr[j], acc[i][j], 0,0,0);
    }
    WAIT_VM0(); BARRIER();
  }

  #pragma unroll
  for (int i=0;i<MI;i++){
    #pragma unroll
    for (int j=0;j<4;j++){
      int gcol = n0 + wc*64 + j*16 + r;
      if (gcol >= Nn) continue;
      float bv = bias ? bias[gcol] : 0.f;
      #pragma unroll
      for (int rr=0; rr<4; rr++){
        int grow = m0 + wr*WSPAN + i*16 + kq*4 + rr;
        if (grow >= M) continue;
        float v = acc[i][j][rr] + bv;
        if constexpr (EPI==0){
          ((float*)out)[(long)z*cBatch + (long)grow*ldc + gcol] = v;
        } else if constexpr (EPI==1){
          ((u16*)out)[(long)z*cBatch + (long)grow*ldc + gcol] = f2bf(v);
        } else if constexpr (EPI==2){
          long idx = (long)z*cBatch + (long)grow*ldc + gcol;
          ((float*)out)[idx] = aux[idx] + v;
        } else if constexpr (EPI==3){
          float g = v / (1.f + __expf(-1.702f*v));
          ((u16*)out)[(long)z*cBatch + (long)grow*ldc + gcol] = f2bf(g);
        } else if constexpr (EPI==4){
          float adj = v < 0.f ? 0.f : v;
          float gmv = aux[(long)grow*Nn + gcol];
          ((u16*)out)[(long)z*cBatch + (long)grow*ldc + gcol] = f2bf(adj*gmv);
        } else if constexpr (EPI==5){
          int b = grow/1568, n = grow%1568, tt = n/196, lp = n%196;
          int yrow = (1+lp)*32 + tt*4 + b;
          ((float*)out)[(long)yrow*ldc + gcol] = v;
        } else if constexpr (EPI==6){
          long idx = (long)grow*ldc + gcol;
          int l = grow>>5, rb = grow&31, tt = rb>>2, bb = rb&3;
          ((float*)out)[((long)((bb*8+tt)*197) + l)*512 + gcol] = aux[idx] + v;
        } else if constexpr (EPI==7){
          ((float*)out)[(long)grow*ldc + gcol] = v;
          int l = grow%197;
          if (l == 0){
            int bt = grow/197, bb = bt>>3, tt = bt&7;
            ((float*)aux)[(tt*4+bb)*512 + gcol] = v;   // glob row = t*4+b
          }
        }
      }
    }
  }
}

// ---------------------------------------------------------------- fused LN + GEMM for M=32 message blocks
// A = LN(X[32][512]) computed once into LDS; B-only staged K-loop (K=512).
// EPI: 1=bf16 out, 3=qgelu bf16 out.
template<int EPI>
__global__ __launch_bounds__(256,2) void msg_ln_gemm(
    const float* __restrict__ X, const float* __restrict__ g, const float* __restrict__ bparm,
    const u16* __restrict__ Bw, const float* __restrict__ bias, u16* __restrict__ out,
    int Nn, int ldc)
{
  __shared__ __align__(16) u16 a_all[32*520];
  __shared__ __align__(16) u16 b_lds[2*8192];
  const int t = threadIdx.x, lane = t&63, wave = t>>6;
  const int wr = wave>>1, wc = wave&1;
  const int r = lane&15, kq = lane>>4;
  const int n0 = blockIdx.x*128;

  // B staging geometry (issue stage-0 FIRST so it flies under the LN work)
  const int srow = t>>3;
  const int scol = ((t&7)*8) ^ ((srow&7)<<3);
  int rowB[4];
  #pragma unroll
  for (int i=0;i<4;i++){ int gb = n0 + i*32 + srow; rowB[i] = gb < Nn ? gb : Nn-1; }
  auto STAGE = [&](int kt, int buf){
    const long koff = (long)kt*64 + scol;
    #pragma unroll
    for (int i=0;i<4;i++)
      gload16(Bw + (long)rowB[i]*512 + koff, (char*)b_lds + buf*16384 + i*4096 + wave*1024);
  };
  STAGE(0,0);

  // LN of X into a_all: (wave, lane>>3) -> row, 8 lanes per row, 64 cols/lane.
  {
    int row = wave*8 + (lane>>3);
    int c0 = (lane&7)*64;
    const float* xr = X + row*512 + c0;
    float s = 0.f, ss = 0.f;
    #pragma unroll
    for (int i=0;i<16;i++){
      float4 v = ((const float4*)xr)[i];
      s  += v.x+v.y+v.z+v.w;
      ss += v.x*v.x+v.y*v.y+v.z*v.z+v.w*v.w;
    }
    #pragma unroll
    for (int d=1; d<8; d<<=1){ s += __shfl_xor(s,d); ss += __shfl_xor(ss,d); }
    float mean = s*(1.f/512.f);
    float rs = rsqrtf(ss*(1.f/512.f) - mean*mean + 1e-5f);
    u16* arow = a_all + row*520 + c0;
    #pragma unroll
    for (int i=0;i<16;i++){
      float4 v  = ((const float4*)xr)[i];
      float4 gv = ((const float4*)(g + c0))[i];
      float4 bv = ((const float4*)(bparm + c0))[i];
      ushort4 o = { f2bf((v.x-mean)*rs*gv.x + bv.x), f2bf((v.y-mean)*rs*gv.y + bv.y),
                    f2bf((v.z-mean)*rs*gv.z + bv.z), f2bf((v.w-mean)*rs*gv.w + bv.w) };
      *(ushort4*)(arow + i*4) = o;
    }
  }
  WAIT_ALL0(); BARRIER();

  f32x4 acc[4] = {};
  for (int kt=0; kt<8; kt++){
    const int cur = kt&1;
    if (kt+1 < 8) STAGE(kt+1, cur^1);
    const u16* bl = b_lds + cur*8192;
    #pragma unroll
    for (int kk=0; kk<2; kk++){
      int rw = wr*16 + r;
      bf16x8 af = *(const bf16x8*)&a_all[rw*520 + kt*64 + kk*32 + kq*8];
      #pragma unroll
      for (int j=0;j<4;j++){
        int rw2 = wc*64 + j*16 + r;
        bf16x8 bfr = *(const bf16x8*)&bl[rw2*64 + ((kk*32 + kq*8) ^ ((rw2&7)<<3))];
        acc[j] = __builtin_amdgcn_mfma_f32_16x16x32_bf16(af, bfr, acc[j], 0,0,0);
      }
    }
    WAIT_VM0(); BARRIER();
  }

  #pragma unroll
  for (int j=0;j<4;j++){
    int gcol = n0 + wc*64 + j*16 + r;
    if (gcol >= Nn) continue;
    float bv = bias[gcol];
    #pragma unroll
    for (int rr=0;rr<4;rr++){
      int grow = wr*16 + kq*4 + rr;
      float v = acc[j][rr] + bv;
      if constexpr (EPI==3) v = v / (1.f + __expf(-1.702f*v));
      out[(long)grow*ldc + gcol] = f2bf(v);
    }
  }
}

// ---------------------------------------------------------------- V transpose
__global__ __launch_bounds__(256) void transpose_v(
    const u16* __restrict__ src, u16* __restrict__ vt,
    int nrows, long zofs, long nofs, int vcol0, int outld)
{
  __shared__ u16 tile[64][66];
  const int t = threadIdx.x;
  const int nt = blockIdx.x, h = blockIdx.y, z = blockIdx.z;
  const int n0 = nt*64;
  const int rlo = t>>3, c0 = (t&7)*8;
  #pragma unroll
  for (int i=0;i<2;i++){
    int nl = i*32 + rlo;
    int n = n0 + nl; int nc = n < nrows ? n : nrows-1;
    const u16* s = src + (long)z*zofs + (long)nc*nofs + vcol0 + h*64 + c0;
    uint4 v = *(const uint4*)s;
    bool dead = n >= nrows;
    #pragma unroll
    for (int e=0;e<8;e++) tile[nl][c0+e] = dead ? (u16)0 : ((const u16*)&v)[e];
  }
  __syncthreads();
  #pragma unroll
  for (int i=0;i<2;i++){
    int d = i*32 + rlo;
    u16 tmp[8];
    #pragma unroll
    for (int e=0;e<8;e++) tmp[e] = tile[c0+e][d];
    int ncol = n0 + c0;
    if (ncol + 8 <= outld){
      u16* dst = vt + ((long)((z*8+h)*64 + d))*outld + ncol;
      *(uint4*)dst = *(uint4*)tmp;
    }
  }
}

// ---------------------------------------------------------------- flash (round-9 best: swapped QK^T, 2 q-tiles/block)
template<bool MASKED>
__global__ __launch_bounds__(256,3) void flash4(
    const u16* __restrict__ QKV, const u16* __restrict__ VT,
    const u16* __restrict__ gmask, u16* __restrict__ Out,
    int nq, int nk, int nqb, long qBatch, long qRow,
    long oBatch, long oRow, long gmBatch, int vtld)
{
  __shared__ __align__(16) u16 k_lds[2*4096];      // [buf][64 key][64 d] swz
  __shared__ __align__(16) u16 p_lds[4][2][1024];  // [wave][qtile][...]
  int h, z, qb;
  if constexpr (MASKED){
    int id = blockIdx.x;
    int a = id>>6, c = id&7; h = (id>>3)&7;
    int G = a*8 + c;
    if (G >= 4*nqb) return;
    z = G / nqb; qb = G % nqb;
  } else {
    qb = blockIdx.x; h = blockIdx.y; z = blockIdx.z;
  }
  const int t = threadIdx.x, lane = t&63, wave = t>>6;
  const int r = lane&15, kq = lane>>4;
  const u16* Qb = QKV + (long)z*qBatch + h*64;
  const u16* Kb = Qb + 512;
  const u16* Vt = VT + (long)(z*8+h)*64*vtld;
  const int qt0 = qb*128;

  int qi[2], qc[2];
  bf16x8 qf[2][2];
  const u16* Gq[2];
  #pragma unroll
  for (int qt=0; qt<2; qt++){
    qi[qt] = qt0 + qt*64 + wave*16 + r;
    qc[qt] = qi[qt] < nq ? qi[qt] : nq-1;
    const u16* qp = Qb + (long)qc[qt]*qRow + kq*8;
    qf[qt][0] = scale8(*(const bf16x8*)qp, 0.125f);
    qf[qt][1] = scale8(*(const bf16x8*)(qp+32), 0.125f);
    Gq[qt] = MASKED ? (gmask + (long)z*gmBatch + (long)qc[qt]*nk) : nullptr;
  }

  const int srow = t>>3;                       // 0..31
  const int scol = ((t&7)*8) ^ ((srow&7)<<3);

  auto stage_k = [&](int kt, int buf){
    #pragma unroll
    for (int i=0;i<2;i++){
      int j = kt*64 + i*32 + srow; if (j > nk-1) j = nk-1;
      gload16(Kb + (long)j*qRow + scol, (char*)k_lds + buf*8192 + i*4096 + wave*1024);
    }
  };

  bf16x8 ONES;
  #pragma unroll
  for (int e=0;e<8;e++) ONES[e] = (short)0x3F80;   // bf16 1.0

  float m_[2] = {-FINF,-FINF};
  f32x4 o_[2][4] = {};  f32x4 l_[2] = {};

  const int nkt = (nk + 63) >> 6;
  stage_k(0,0);
  __syncthreads();
  for (int kt=0; kt<nkt; kt++){
    const int cur = kt&1;
    if (kt+1 < nkt) stage_k(kt+1, cur^1);     // flies during this tile's compute

    // shared V^T fragments, issued early (land under QK^T)
    uint4 vfr[2][4];
    #pragma unroll
    for (int c=0;c<2;c++)
      #pragma unroll
      for (int j=0;j<4;j++)
        vfr[c][j] = *(const uint4*)(Vt + (long)(j*16+r)*vtld + kt*64 + c*32 + kq*8);

    const u16* kl = k_lds + cur*4096;
    #pragma unroll
    for (int qt=0; qt<2; qt++){
      ushort4 gv[4];
      if constexpr (MASKED){
        #pragma unroll
        for (int sub=0;sub<4;sub++)
          gv[sub] = *(const ushort4*)(Gq[qt] + kt*64 + sub*16 + kq*4);
      }

      // ---- QK^T swapped: p[sub][rr], key = kt*64+sub*16+kq*4+rr, col=q(r)
      float p[4][4];
      #pragma unroll
      for (int sub=0; sub<4; sub++){
        int rw = sub*16 + r; int sw = (rw&7)<<3;
        bf16x8 kf0 = *(const bf16x8*)&kl[rw*64 + ((kq*8) ^ sw)];
        bf16x8 kf1 = *(const bf16x8*)&kl[rw*64 + ((32 + kq*8) ^ sw)];
        f32x4 sc = {};
        sc = __builtin_amdgcn_mfma_f32_16x16x32_bf16(kf0, qf[qt][0], sc, 0,0,0);
        sc = __builtin_amdgcn_mfma_f32_16x16x32_bf16(kf1, qf[qt][1], sc, 0,0,0);
        #pragma unroll
        for (int rr=0;rr<4;rr++){
          float sv = sc[rr];
          int key = kt*64 + sub*16 + kq*4 + rr;
          if constexpr (MASKED){
            u16 g = ((const u16*)&gv[sub])[rr];
            sv = (g == 0 || key >= nk) ? -FINF : sv * bf2f(g);
          } else {
            if (key >= nk) sv = -FINF;
          }
          p[sub][rr] = sv;
        }
      }

      // ---- max: in-lane tree over 16, then 2 shfl across kq groups
      float mx;
      { float a0 = fmaxf(fmaxf(p[0][0],p[0][1]), fmaxf(p[0][2],p[0][3]));
        float a1 = fmaxf(fmaxf(p[1][0],p[1][1]), fmaxf(p[1][2],p[1][3]));
        float a2 = fmaxf(fmaxf(p[2][0],p[2][1]), fmaxf(p[2][2],p[2][3]));
        float a3 = fmaxf(fmaxf(p[3][0],p[3][1]), fmaxf(p[3][2],p[3][3]));
        mx = fmaxf(fmaxf(a0,a1), fmaxf(a2,a3)); }
      mx = fmaxf(mx, __shfl_xor(mx, 16));
      mx = fmaxf(mx, __shfl_xor(mx, 32));
      float mnew = fmaxf(m_[qt], mx);
      if (__any(mnew > m_[qt])){               // skip rescale when max unchanged
        float fac = (m_[qt] == -FINF) ? 0.f : __expf(m_[qt] - mnew);
        #pragma unroll
        for (int j=0;j<4;j++){ o_[qt][j][0]*=fac; o_[qt][j][1]*=fac; o_[qt][j][2]*=fac; o_[qt][j][3]*=fac; }
        l_[qt][0]*=fac; l_[qt][1]*=fac; l_[qt][2]*=fac; l_[qt][3]*=fac;
        m_[qt] = mnew;
      }
      mnew = m_[qt];

      // ---- exp + pack + p_lds writes (wave-private slot per q-tile)
      #pragma unroll
      for (int sub=0;sub<4;sub++){
        float e0 = (p[sub][0] == -FINF) ? 0.f : __expf(p[sub][0] - mnew);
        float e1 = (p[sub][1] == -FINF) ? 0.f : __expf(p[sub][1] - mnew);
        float e2 = (p[sub][2] == -FINF) ? 0.f : __expf(p[sub][2] - mnew);
        float e3 = (p[sub][3] == -FINF) ? 0.f : __expf(p[sub][3] - mnew);
        unsigned u0, u1;
        asm volatile("v_cvt_pk_bf16_f32 %0, %1, %2" : "=v"(u0) : "v"(e0), "v"(e1));
        asm volatile("v_cvt_pk_bf16_f32 %0, %1, %2" : "=v"(u1) : "v"(e2), "v"(e3));
        uint2 w; w.x = u0; w.y = u1;
        int idx = r*64 + ((sub*16 + kq*4) ^ ((r&7)<<3));
        *(uint2*)&p_lds[wave][qt][idx] = w;
      }

      // ---- PV: O^T[d][q] += V^T-frag x P-frag ; l via ones-MFMA
      #pragma unroll
      for (int c=0;c<2;c++){
        bf16x8 pf = *(const bf16x8*)&p_lds[wave][qt][r*64 + ((c*32 + kq*8) ^ ((r&7)<<3))];
        #pragma unroll
        for (int j=0;j<4;j++){
          bf16x8 vf = *(const bf16x8*)&vfr[c][j];
          o_[qt][j] = __builtin_amdgcn_mfma_f32_16x16x32_bf16(vf, pf, o_[qt][j], 0,0,0);
        }
        l_[qt] = __builtin_amdgcn_mfma_f32_16x16x32_bf16(ONES, pf, l_[qt], 0,0,0);
      }
    }
    __syncthreads();   // next K buffer staged (drains gloads) + protects reuse
  }

  #pragma unroll
  for (int qt=0; qt<2; qt++){
    float inv = l_[qt][0] > 0.f ? 1.f/l_[qt][0] : 0.f;
    if (qi[qt] < nq){
      #pragma unroll
      for (int j=0;j<4;j++){
        ushort4 ov = { f2bf(o_[qt][j][0]*inv), f2bf(o_[qt][j][1]*inv),
                       f2bf(o_[qt][j][2]*inv), f2bf(o_[qt][j][3]*inv) };
        *(ushort4*)(Out + (long)z*oBatch + (long)qi[qt]*oRow + h*64 + j*16 + kq*4) = ov;
      }
    }
  }
}

// ---------------------------------------------------------------- LayerNorm rows of 512, f32 in -> bf16 out
__global__ __launch_bounds__(256) void ln_rows(const float* __restrict__ in,
    const float* __restrict__ g, const float* __restrict__ b, u16* __restrict__ out, int rows)
{
  int wave = threadIdx.x >> 6, lane = threadIdx.x & 63;
  int row = blockIdx.x*4 + wave;
  if (row >= rows) return;
  const float4* x = (const float4*)(in + (long)row*512);
  float4 v0 = x[lane], v1 = x[lane+64];
  float s  = v0.x+v0.y+v0.z+v0.w + v1.x+v1.y+v1.z+v1.w;
  float ss = v0.x*v0.x+v0.y*v0.y+v0.z*v0.z+v0.w*v0.w + v1.x*v1.x+v1.y*v1.y+v1.z*v1.z+v1.w*v1.w;
  #pragma unroll
  for (int d=1; d<64; d<<=1){ s += __shfl_xor(s,d); ss += __shfl_xor(ss,d); }
  float mean = s * (1.f/512.f);
  float var = ss * (1.f/512.f) - mean*mean;
  float rs = rsqrtf(var + 1e-5f);
  const float4* gg = (const float4*)g; const float4* bb = (const float4*)b;
  float4 g0 = gg[lane], g1 = gg[lane+64], b0 = bb[lane], b1 = bb[lane+64];
  u16* o = out + (long)row*512;
  ushort4 o0 = { f2bf((v0.x-mean)*rs*g0.x + b0.x), f2bf((v0.y-mean)*rs*g0.y + b0.y),
                 f2bf((v0.z-mean)*rs*g0.z + b0.z), f2bf((v0.w-mean)*rs*g0.w + b0.w) };
  ushort4 o1 = { f2bf((v1.x-mean)*rs*g1.x + b1.x), f2bf((v1.y-mean)*rs*g1.y + b1.y),
                 f2bf((v1.z-mean)*rs*g1.z + b1.z), f2bf((v1.w-mean)*rs*g1.w + b1.w) };
  *(ushort4*)(o + lane*4) = o0;
  *(ushort4*)(o + 256 + lane*4) = o1;
}

// ---------------------------------------------------------------- loc rows: write xn (L2-normalized) and plain bf16 copy
__global__ __launch_bounds__(256) void locprep(const float* __restrict__ y0,
    u16* __restrict__ xn, u16* __restrict__ locb)
{
  int wave = threadIdx.x >> 6, lane = threadIdx.x & 63;
  int rr = blockIdx.x*4 + wave;                 // 0..6271 = b*1568 + t*196 + lp
  int bb = rr/1568, n = rr%1568, tt = n/196, lp = n%196;
  const float4* x = (const float4*)(y0 + ((long)((bb*8+tt)*197) + 1 + lp)*512);
  float4 v0 = x[lane], v1 = x[lane+64];
  float ss = v0.x*v0.x+v0.y*v0.y+v0.z*v0.z+v0.w*v0.w + v1.x*v1.x+v1.y*v1.y+v1.z*v1.z+v1.w*v1.w;
  #pragma unroll
  for (int d=1; d<64; d<<=1) ss += __shfl_xor(ss,d);
  float sc = 1.f / fmaxf(sqrtf(ss), 1e-12f);
  u16* ox = xn + (long)rr*512;
  u16* ol = locb + (long)rr*512;
  ushort4 a0 = { f2bf(v0.x*sc), f2bf(v0.y*sc), f2bf(v0.z*sc), f2bf(v0.w*sc) };
  ushort4 a1 = { f2bf(v1.x*sc), f2bf(v1.y*sc), f2bf(v1.z*sc), f2bf(v1.w*sc) };
  ushort4 c0 = { f2bf(v0.x), f2bf(v0.y), f2bf(v0.z), f2bf(v0.w) };
  ushort4 c1 = { f2bf(v1.x), f2bf(v1.y), f2bf(v1.z), f2bf(v1.w) };
  *(ushort4*)(ox + lane*4) = a0;  *(ushort4*)(ox + 256 + lane*4) = a1;
  *(ushort4*)(ol + lane*4) = c0;  *(ushort4*)(ol + 256 + lane*4) = c1;
}

// ---------------------------------------------------------------- tiny message-path attention S=8,Bt=4,H=8
__global__ __launch_bounds__(64) void msg_attn(const u16* __restrict__ mqkv, u16* __restrict__ matt){
  __shared__ float q_s[8][64], k_s[8][64], v_s[8][64];
  int bh = blockIdx.x; int bt = bh>>3, h = bh&7;
  int lane = threadIdx.x;
  int row = lane>>3, cc = (lane&7)*8;
  #pragma unroll
  for (int e=0;e<8;e++){
    long base = (long)(row*4 + bt)*1536 + h*64 + cc + e;
    q_s[row][cc+e] = bf2f(mqkv[base]);
    k_s[row][cc+e] = bf2f(mqkv[base + 512]);
    v_s[row][cc+e] = bf2f(mqkv[base + 1024]);
  }
  __syncthreads();
  int q = lane>>3, k = lane&7;
  float s = 0.f;
  #pragma unroll 16
  for (int d=0; d<64; d++) s += q_s[q][d]*k_s[k][d];
  s *= 0.125f;
  float mx = s;
  #pragma unroll
  for (int d=1; d<8; d<<=1) mx = fmaxf(mx, __shfl_xor(mx,d));
  float p = __expf(s - mx), ps = p;
  #pragma unroll
  for (int d=1; d<8; d<<=1) ps += __shfl_xor(ps,d);
  p /= ps;
  for (int d=0; d<64; d++){
    float ov = p * v_s[k][d];
    #pragma unroll
    for (int m=1; m<8; m<<=1) ov += __shfl_xor(ov,m);
    if (k == (d>>3)) matt[(long)(q*4 + bt)*512 + h*64 + d] = f2bf(ov);
  }
}

// ---------------------------------------------------------------- small copies
__global__ __launch_bounds__(256) void copy32(const float* __restrict__ glob, float* __restrict__ y){
  int idx = blockIdx.x*256 + threadIdx.x;
  y[idx] = glob[idx];
}

// ---------------------------------------------------------------- launch
extern "C" void kernel_launch(void* const* d_in, const int* in_sizes, int n_in,
                              void* d_out, int out_size, void* d_ws, size_t ws_size,
                              hipStream_t stream)
{
  const float* x      = (const float*)d_in[0];
  const float* proj_w = (const float*)d_in[1];
  const float* proj_b = (const float*)d_in[2];
  const float* m_ln1g = (const float*)d_in[3];
  const float* m_ln1b = (const float*)d_in[4];
  const float* m_inw  = (const float*)d_in[5];
  const float* m_inb  = (const float*)d_in[6];
  const float* m_outw = (const float*)d_in[7];
  const float* m_outb = (const float*)d_in[8];
  const float* m_ln2g = (const float*)d_in[9];
  const float* m_ln2b = (const float*)d_in[10];
  const float* m_fcw  = (const float*)d_in[11];
  const float* m_fcb  = (const float*)d_in[12];
  const float* m_pw   = (const float*)d_in[13];
  const float* m_pb   = (const float*)d_in[14];
  const float* g_wq = (const float*)d_in[15]; const float* g_bq = (const float*)d_in[16];
  const float* g_wk = (const float*)d_in[17]; const float* g_bk = (const float*)d_in[18];
  const float* g_wv = (const float*)d_in[19]; const float* g_bv = (const float*)d_in[20];
  const float* g_wo = (const float*)d_in[21]; const float* g_bo = (const float*)d_in[22];
  const float* ln1g = (const float*)d_in[23]; const float* ln1b = (const float*)d_in[24];
  const float* a_inw = (const float*)d_in[25]; const float* a_inb = (const float*)d_in[26];
  const float* a_outw = (const float*)d_in[27]; const float* a_outb = (const float*)d_in[28];
  const float* ln2g = (const float*)d_in[29]; const float* ln2b = (const float*)d_in[30];
  const float* fcw = (const float*)d_in[31]; const float* fcb = (const float*)d_in[32];
  const float* pw = (const float*)d_in[33]; const float* pb = (const float*)d_in[34];
  const float* g_mask = (const float*)d_in[35];

  if (ws_size < (size_t)99753984) return;

  char* ws = (char*)d_ws;
  u16* WB = (u16*)ws;
  const long WPROJ=0, WMIN=262144, WMOUT=1048576, WMFC=1310720, WMP=2359296,
             WGQ=3407872, WGK=3670016, WGV=3932160, WGO=4194304,
             WAIN=4456448, WAOUT=5242880, WFC=5505024, WP=6553600;
  float* y0   = (float*)(ws + 15204352);
  float* y    = (float*)(ws + 28114944);
  u16* lnbuf  = (u16*)(ws + 41025536);    // xn / ln outputs [6304][512]; aliases vtg
  u16* vtg    = (u16*)(ws + 41025536);    // masked V^T [4*8*64][1568]
  u16* locb   = (u16*)(ws + 47480832);    // [6272][512]
  u16* qkv    = (u16*)(ws + 53903360);    // [6304][1536]
  u16* xb     = (u16*)(ws + 73269248);    // aliases gm / hbuf / vt2
  u16* gm     = (u16*)(ws + 73269248);    // [4][1568][1568] bf16
  u16* vt2    = (u16*)(ws + 73269248);    // unmasked V^T [32*8*64][256]
  u16* hbuf   = (u16*)(ws + 73269248);    // [6304][2048] bf16
  u16* obuf   = (u16*)(ws + 92938240);    // [6304][512] bf16
  float* glob = (float*)(ws + 99393536);  // [32][512] f32
  u16* mqkv   = (u16*)(ws + 99491840);
  u16* matt   = (u16*)(ws + 99590144);
  u16* mh     = (u16*)(ws + 99622912);
  float* gbias = (float*)(ws + 99622912); // aliases mh (dead after message blocks)

  // 1. all f32->bf16 conversions (weights + x)
  CvtArgs ca;
  auto setseg=[&](int i, const float* s, u16* d, int n){ ca.src[i]=s; ca.dst[i]=d; ca.n[i]=n; };
  setseg(0,  x,      xb,       6304*512);
  setseg(1,  proj_w, WB+WPROJ, 262144);
  setseg(2,  m_inw,  WB+WMIN,  786432);
  setseg(3,  m_outw, WB+WMOUT, 262144);
  setseg(4,  m_fcw,  WB+WMFC,  1048576);
  setseg(5,  m_pw,   WB+WMP,   1048576);
  setseg(6,  g_wq,   WB+WGQ,   262144);
  setseg(7,  g_wk,   WB+WGK,   262144);
  setseg(8,  g_wv,   WB+WGV,   262144);
  setseg(9,  g_wo,   WB+WGO,   262144);
  setseg(10, a_inw,  WB+WAIN,  786432);
  setseg(11, a_outw, WB+WAOUT, 262144);
  setseg(12, fcw,    WB+WFC,   1048576);
  setseg(13, pw,     WB+WP,    1048576);
  cvt_multi<<<dim3(128,14), 256, 0, stream>>>(ca);

  // 2. x @ proj_w^T + proj_b -> y0 (f32); l==0 rows side-written to glob
  gemm_nt<32,7,4><<<dim3(4,197), 256, 0, stream>>>(xb, WB+WPROJ, proj_b, (const float*)glob, y0, 6304,512,512,512, 0,0,0);

  // 3. message-passing resblock x2 (LN fused into the two LN'd GEMMs)
  for (int it=0; it<2; ++it){
    msg_ln_gemm<1><<<12,256,0,stream>>>(glob, m_ln1g, m_ln1b, WB+WMIN, m_inb, mqkv, 1536, 1536);
    msg_attn<<<32,64,0,stream>>>(mqkv, matt);
    gemm_nt<32,2,4><<<dim3(4,1),256,0,stream>>>(matt, WB+WMOUT, m_outb, glob, glob, 32,512,512,512, 0,0,0);
    msg_ln_gemm<3><<<16,256,0,stream>>>(glob, m_ln2g, m_ln2b, WB+WMFC, m_fcb, mh, 2048, 2048);
    gemm_nt<32,2,4><<<dim3(4,1),256,0,stream>>>(mh, WB+WMP, m_pb, glob, glob, 32,512,2048,512, 0,0,0);
  }

  // 3b. concat graph-attention biases into gbias[1536] (mh region now dead)
  concat_bias<<<6,256,0,stream>>>(g_bq, g_bk, g_bv, gbias);

  // 4. loc rows -> xn (normalized, ->lnbuf) + plain bf16 (->locb)
  locprep<<<1568,256,0,stream>>>(y0, lnbuf, locb);

  // 5. sim = xn@xn^T per batch; gm = relu-thresholded * g_mask (bf16)
  gemm_nt<64,4,3><<<dim3(13,25,4),256,0,stream>>>(lnbuf, lnbuf, nullptr, g_mask, gm,
      1568,1568,512,1568, 1568L*512, 1568L*512, 1568L*1568);

  // 6. graph Q,K,V fused projection -> qkv[6272][1536]  (xn dead after step 5)
  gemm_nt<64,1,3><<<dim3(12,98),256,0,stream>>>(locb, WB+WGQ, gbias, nullptr, qkv, 6272,1536,512,1536, 0,0,0);

  // 6b. V^T for graph attention -> vtg (in dead lnbuf region)
  transpose_v<<<dim3(25,8,4),256,0,stream>>>(qkv, vtg, 1568, 1568L*1536, 1536L, 1024, 1568);

  // 7. masked graph attention -> obuf[6272][512]; heads of a (z,qtile) share an XCD
  //    nqb = 13; groups = 4*13 = 52; blocks = ceil(52/8)*64 = 448
  flash4<true><<<448,256,0,stream>>>(qkv, vtg, gm, obuf,
      1568,1568,13, 1568L*1536, 1536, 1568L*512, 512, 1568L*1568, 1568);

  // 8. out-proj with row permutation directly into y rows 32..6303
  gemm_nt<32,5,4><<<dim3(4,196),256,0,stream>>>(obuf, WB+WGO, g_bo, nullptr, y, 6272,512,512,512, 0,0,0);

  // 9. y rows 0..31 = glob
  copy32<<<64,256,0,stream>>>(glob, y);

  // 10-13. final MHA: y += attn(ln(y))
  ln_rows<<<1576,256,0,stream>>>(y, ln1g, ln1b, lnbuf, 6304);
  gemm_nt<64,1,3><<<dim3(12,99),256,0,stream>>>(lnbuf, WB+WAIN, a_inb, nullptr, qkv, 6304,1536,512,1536, 0,0,0);
  transpose_v<<<dim3(4,8,32),256,0,stream>>>(qkv, vt2, 197, 1536L, 32L*1536, 1024, 256);
  flash4<false><<<dim3(2,8,32),256,0,stream>>>(qkv, vt2, nullptr, obuf,
      197,197,2, 1536, 32L*1536, 512, 32L*512, 0, 256);
  gemm_nt<32,2,4><<<dim3(4,197),256,0,stream>>>(obuf, WB+WAOUT, a_outb, y, y, 6304,512,512,512, 0,0,0);

  // 14-16. MLP: y += qgelu(ln2(y)@fcw^T+fcb)@pw^T+pb ; p-proj fuses out-permute
  ln_rows<<<1576,256,0,stream>>>(y, ln2g, ln2b, lnbuf, 6304);
  gemm_nt<64,3,3><<<dim3(16,99),256,0,stream>>>(lnbuf, WB+WFC, fcb, nullptr, hbuf, 6304,2048,512,2048, 0,0,0);
  gemm_nt<32,6,4><<<dim3(4,197),256,0,stream>>>(hbuf, WB+WP, pb, y, (float*)d_out, 6304,512,2048,512, 0,0,0);
}

// Round 13
// 534.228 us; speedup vs baseline: 1.0022x; 1.0022x over previous
//
#include <hip/hip_runtime.h>
#include <hip/hip_bf16.h>

typedef unsigned short u16;
typedef __attribute__((ext_vector_type(8))) short bf16x8;
typedef __attribute__((ext_vector_type(4))) float f32x4;

#define FINF __builtin_huge_valf()

static __device__ __forceinline__ float bf2f(u16 v){ union{unsigned u; float f;} c; c.u = ((unsigned)v)<<16; return c.f; }
static __device__ __forceinline__ u16 f2bf(float f){ union{__hip_bfloat16 h; u16 u;} c; c.h = __float2bfloat16(f); return c.u; }
static __device__ __forceinline__ bf16x8 scale8(bf16x8 v, float s){
  bf16x8 o;
  #pragma unroll
  for (int e=0;e<8;e++) o[e] = (short)f2bf(bf2f((u16)v[e])*s);
  return o;
}

// async global->LDS, 16B per lane; LDS dest = wave-uniform base + lane*16
static __device__ __forceinline__ void gload16(const void* g, void* l){
  __builtin_amdgcn_global_load_lds(
      (const __attribute__((address_space(1))) void*)g,
      (__attribute__((address_space(3))) void*)l, 16, 0, 0);
}

// raw-barrier pipeline primitives (rule #18)
#define WAIT_VM0()   { asm volatile("s_waitcnt vmcnt(0)" ::: "memory"); __builtin_amdgcn_sched_barrier(0); }
#define BARRIER()    { __builtin_amdgcn_sched_barrier(0); __builtin_amdgcn_s_barrier(); __builtin_amdgcn_sched_barrier(0); }

// ---------------------------------------------------------------- cvt
struct CvtArgs {
  const float* src[14];
  u16* dst[14];
  int n[14];
};
__global__ __launch_bounds__(256) void cvt_multi(CvtArgs a){
  int seg = blockIdx.y;
  const float* s = a.src[seg]; u16* d = a.dst[seg]; int n = a.n[seg];
  for (int i = (blockIdx.x*256 + threadIdx.x)*4; i < n; i += gridDim.x*256*4){
    float4 v = *(const float4*)(s + i);
    ushort4 o = { f2bf(v.x), f2bf(v.y), f2bf(v.z), f2bf(v.w) };
    *(ushort4*)(d + i) = o;
  }
}

__global__ __launch_bounds__(256) void concat_bias(const float* a, const float* b, const float* c, float* o){
  int i = blockIdx.x*256 + threadIdx.x;   // 1536
  o[i] = i < 512 ? a[i] : (i < 1024 ? b[i-512] : c[i-1024]);
}

// ---------------------------------------------------------------- GEMM  C = A @ B^T (+bias, epilogues)
// (round-9 config: 2-buffer, vmcnt(0)+barrier — measured best)
template<int BM, int EPI, int MW>
__global__ __launch_bounds__(256,MW) void gemm_nt(
    const u16* __restrict__ A, const u16* __restrict__ Bw,
    const float* __restrict__ bias, const float* aux, void* out,
    int M, int Nn, int K, int ldc, long aBatch, long bBatch, long cBatch)
{
  constexpr int MI = BM/32;
  constexpr int WSPAN = BM/2;
  __shared__ __align__(16) u16 a_lds[2*BM*64];
  __shared__ __align__(16) u16 b_lds[2*128*64];
  const int z = blockIdx.z;
  const u16* Az = A + (long)z*aBatch;
  const u16* Bz = Bw + (long)z*bBatch;
  const int n0 = blockIdx.x*128, m0 = blockIdx.y*BM;
  const int t = threadIdx.x, lane = t & 63, wave = t >> 6;
  const int wr = wave >> 1, wc = wave & 1;
  const int r = lane & 15, kq = lane >> 4;

  const int srow = t >> 3;                        // 0..31
  const int scol = ((t&7)*8) ^ ((srow&7)<<3);     // swizzled source col (u16)
  int rowA[MI], rowB[4];
  #pragma unroll
  for (int i=0;i<MI;i++){ int ga = m0 + i*32 + srow; rowA[i] = ga < M ? ga : M-1; }
  #pragma unroll
  for (int i=0;i<4;i++){ int gb = n0 + i*32 + srow; rowB[i] = gb < Nn ? gb : Nn-1; }

  f32x4 acc[MI][4] = {};
  const int nkt = K >> 6;

  auto STAGE = [&](int kt, int buf){
    const long koff = (long)kt*64 + scol;
    #pragma unroll
    for (int i=0;i<MI;i++)
      gload16(Az + (long)rowA[i]*K + koff, (char*)a_lds + buf*(BM*128) + i*4096 + wave*1024);
    #pragma unroll
    for (int i=0;i<4;i++)
      gload16(Bz + (long)rowB[i]*K + koff, (char*)b_lds + buf*16384 + i*4096 + wave*1024);
  };

  STAGE(0,0);
  WAIT_VM0(); BARRIER();
  for (int kt=0; kt<nkt; kt++){
    const int cur = kt&1;
    if (kt+1 < nkt) STAGE(kt+1, cur^1);
    const u16* al = a_lds + cur*BM*64;
    const u16* bl = b_lds + cur*8192;
    #pragma unroll
    for (int kk=0; kk<2; kk++){
      bf16x8 af[MI], bfr[4];
      #pragma unroll
      for (int i=0;i<MI;i++){
        int rw = wr*WSPAN + i*16 + r;
        af[i] = *(const bf16x8*)&al[rw*64 + ((kk*32 + kq*8) ^ ((rw&7)<<3))];
      }
      #pragma unroll
      for (int j=0;j<4;j++){
        int rw = wc*64 + j*16 + r;
        bfr[j] = *(const bf16x8*)&bl[rw*64 + ((kk*32 + kq*8) ^ ((rw&7)<<3))];
      }
      #pragma unroll
      for (int i=0;i<MI;i++)
        #pragma unroll
        for (int j=0;j<4;j++)
          acc[i][j] = __builtin_amdgcn_mfma_f32_16x16x32_bf16(af[i], bfr[j], acc[i][j], 0,0,0);
    }
    WAIT_VM0(); BARRIER();
  }

  #pragma unroll
  for (int i=0;i<MI;i++){
    #pragma unroll
    for (int j=0;j<4;j++){
      int gcol = n0 + wc*64 + j*16 + r;
      if (gcol >= Nn) continue;
      float bv = bias ? bias[gcol] : 0.f;
      #pragma unroll
      for (int rr=0; rr<4; rr++){
        int grow = m0 + wr*WSPAN + i*16 + kq*4 + rr;
        if (grow >= M) continue;
        float v = acc[i][j][rr] + bv;
        if constexpr (EPI==0){
          ((float*)out)[(long)z*cBatch + (long)grow*ldc + gcol] = v;
        } else if constexpr (EPI==1){
          ((u16*)out)[(long)z*cBatch + (long)grow*ldc + gcol] = f2bf(v);
        } else if constexpr (EPI==2){
          long idx = (long)z*cBatch + (long)grow*ldc + gcol;
          ((float*)out)[idx] = aux[idx] + v;
        } else if constexpr (EPI==3){
          float g = v / (1.f + __expf(-1.702f*v));
          ((u16*)out)[(long)z*cBatch + (long)grow*ldc + gcol] = f2bf(g);
        } else if constexpr (EPI==4){
          float adj = v < 0.f ? 0.f : v;
          float gmv = aux[(long)grow*Nn + gcol];
          ((u16*)out)[(long)z*cBatch + (long)grow*ldc + gcol] = f2bf(adj*gmv);
        } else if constexpr (EPI==5){
          int b = grow/1568, n = grow%1568, tt = n/196, lp = n%196;
          int yrow = (1+lp)*32 + tt*4 + b;
          ((float*)out)[(long)yrow*ldc + gcol] = v;
        } else if constexpr (EPI==6){
          long idx = (long)grow*ldc + gcol;
          int l = grow>>5, rb = grow&31, tt = rb>>2, bb = rb&3;
          ((float*)out)[((long)((bb*8+tt)*197) + l)*512 + gcol] = aux[idx] + v;
        }
      }
    }
  }
}

// ---------------------------------------------------------------- V transpose
__global__ __launch_bounds__(256) void transpose_v(
    const u16* __restrict__ src, u16* __restrict__ vt,
    int nrows, long zofs, long nofs, int vcol0, int outld)
{
  __shared__ u16 tile[64][66];
  const int t = threadIdx.x;
  const int nt = blockIdx.x, h = blockIdx.y, z = blockIdx.z;
  const int n0 = nt*64;
  const int rlo = t>>3, c0 = (t&7)*8;
  #pragma unroll
  for (int i=0;i<2;i++){
    int nl = i*32 + rlo;
    int n = n0 + nl; int nc = n < nrows ? n : nrows-1;
    const u16* s = src + (long)z*zofs + (long)nc*nofs + vcol0 + h*64 + c0;
    uint4 v = *(const uint4*)s;
    bool dead = n >= nrows;
    #pragma unroll
    for (int e=0;e<8;e++) tile[nl][c0+e] = dead ? (u16)0 : ((const u16*)&v)[e];
  }
  __syncthreads();
  #pragma unroll
  for (int i=0;i<2;i++){
    int d = i*32 + rlo;
    u16 tmp[8];
    #pragma unroll
    for (int e=0;e<8;e++) tmp[e] = tile[c0+e][d];
    int ncol = n0 + c0;
    if (ncol + 8 <= outld){
      u16* dst = vt + ((long)((z*8+h)*64 + d))*outld + ncol;
      *(uint4*)dst = *(uint4*)tmp;
    }
  }
}

// ---------------------------------------------------------------- flash (r9 structure + exp2 + defer-max THR)
// swapped QK^T, 2 q-tiles/block, shared V^T frags, K via gload_lds dbuf.
// Q pre-scaled by 0.125*log2e so softmax uses exp2 directly (mask multiply
// commutes: (s*log2e)*g). T13: skip o/l rescale unless max grew > 11.5
// (= 8 nats); deferred P values bounded by 2^11.5, safe in bf16/f32-accum.
template<bool MASKED>
__global__ __launch_bounds__(256,3) void flash4(
    const u16* __restrict__ QKV, const u16* __restrict__ VT,
    const u16* __restrict__ gmask, u16* __restrict__ Out,
    int nq, int nk, int nqb, long qBatch, long qRow,
    long oBatch, long oRow, long gmBatch, int vtld)
{
  __shared__ __align__(16) u16 k_lds[2*4096];      // [buf][64 key][64 d] swz
  __shared__ __align__(16) u16 p_lds[4][2][1024];  // [wave][qtile][...]
  int h, z, qb;
  if constexpr (MASKED){
    int id = blockIdx.x;
    int a = id>>6, c = id&7; h = (id>>3)&7;
    int G = a*8 + c;
    if (G >= 4*nqb) return;
    z = G / nqb; qb = G % nqb;
  } else {
    qb = blockIdx.x; h = blockIdx.y; z = blockIdx.z;
  }
  const int t = threadIdx.x, lane = t&63, wave = t>>6;
  const int r = lane&15, kq = lane>>4;
  const u16* Qb = QKV + (long)z*qBatch + h*64;
  const u16* Kb = Qb + 512;
  const u16* Vt = VT + (long)(z*8+h)*64*vtld;
  const int qt0 = qb*128;

  int qi[2], qc[2];
  bf16x8 qf[2][2];
  const u16* Gq[2];
  #pragma unroll
  for (int qt=0; qt<2; qt++){
    qi[qt] = qt0 + qt*64 + wave*16 + r;
    qc[qt] = qi[qt] < nq ? qi[qt] : nq-1;
    const u16* qp = Qb + (long)qc[qt]*qRow + kq*8;
    qf[qt][0] = scale8(*(const bf16x8*)qp, 0.18033688f);      // 0.125*log2(e)
    qf[qt][1] = scale8(*(const bf16x8*)(qp+32), 0.18033688f);
    Gq[qt] = MASKED ? (gmask + (long)z*gmBatch + (long)qc[qt]*nk) : nullptr;
  }

  const int srow = t>>3;                       // 0..31
  const int scol = ((t&7)*8) ^ ((srow&7)<<3);

  auto stage_k = [&](int kt, int buf){
    #pragma unroll
    for (int i=0;i<2;i++){
      int j = kt*64 + i*32 + srow; if (j > nk-1) j = nk-1;
      gload16(Kb + (long)j*qRow + scol, (char*)k_lds + buf*8192 + i*4096 + wave*1024);
    }
  };

  bf16x8 ONES;
  #pragma unroll
  for (int e=0;e<8;e++) ONES[e] = (short)0x3F80;   // bf16 1.0

  float m_[2] = {-FINF,-FINF};
  f32x4 o_[2][4] = {};  f32x4 l_[2] = {};

  const int nkt = (nk + 63) >> 6;
  stage_k(0,0);
  __syncthreads();
  for (int kt=0; kt<nkt; kt++){
    const int cur = kt&1;
    if (kt+1 < nkt) stage_k(kt+1, cur^1);     // flies during this tile's compute

    // shared V^T fragments, issued early (land under QK^T)
    uint4 vfr[2][4];
    #pragma unroll
    for (int c=0;c<2;c++)
      #pragma unroll
      for (int j=0;j<4;j++)
        vfr[c][j] = *(const uint4*)(Vt + (long)(j*16+r)*vtld + kt*64 + c*32 + kq*8);

    const u16* kl = k_lds + cur*4096;
    #pragma unroll
    for (int qt=0; qt<2; qt++){
      ushort4 gv[4];
      if constexpr (MASKED){
        #pragma unroll
        for (int sub=0;sub<4;sub++)
          gv[sub] = *(const ushort4*)(Gq[qt] + kt*64 + sub*16 + kq*4);
      }

      // ---- QK^T swapped: p[sub][rr], key = kt*64+sub*16+kq*4+rr, col=q(r)
      float p[4][4];
      #pragma unroll
      for (int sub=0; sub<4; sub++){
        int rw = sub*16 + r; int sw = (rw&7)<<3;
        bf16x8 kf0 = *(const bf16x8*)&kl[rw*64 + ((kq*8) ^ sw)];
        bf16x8 kf1 = *(const bf16x8*)&kl[rw*64 + ((32 + kq*8) ^ sw)];
        f32x4 sc = {};
        sc = __builtin_amdgcn_mfma_f32_16x16x32_bf16(kf0, qf[qt][0], sc, 0,0,0);
        sc = __builtin_amdgcn_mfma_f32_16x16x32_bf16(kf1, qf[qt][1], sc, 0,0,0);
        #pragma unroll
        for (int rr=0;rr<4;rr++){
          float sv = sc[rr];
          int key = kt*64 + sub*16 + kq*4 + rr;
          if constexpr (MASKED){
            u16 g = ((const u16*)&gv[sub])[rr];
            sv = (g == 0 || key >= nk) ? -FINF : sv * bf2f(g);
          } else {
            if (key >= nk) sv = -FINF;
          }
          p[sub][rr] = sv;
        }
      }

      // ---- max: in-lane tree over 16, then 2 shfl across kq groups
      float mx;
      { float a0 = fmaxf(fmaxf(p[0][0],p[0][1]), fmaxf(p[0][2],p[0][3]));
        float a1 = fmaxf(fmaxf(p[1][0],p[1][1]), fmaxf(p[1][2],p[1][3]));
        float a2 = fmaxf(fmaxf(p[2][0],p[2][1]), fmaxf(p[2][2],p[2][3]));
        float a3 = fmaxf(fmaxf(p[3][0],p[3][1]), fmaxf(p[3][2],p[3][3]));
        mx = fmaxf(fmaxf(a0,a1), fmaxf(a2,a3)); }
      mx = fmaxf(mx, __shfl_xor(mx, 16));
      mx = fmaxf(mx, __shfl_xor(mx, 32));
      // T13 defer-max: rescale only if max grew beyond THR (log2-domain)
      if (!__all(mx - m_[qt] <= 11.5f)){
        float mnew = fmaxf(m_[qt], mx);
        float fac = (m_[qt] == -FINF) ? 0.f : exp2f(m_[qt] - mnew);
        #pragma unroll
        for (int j=0;j<4;j++){ o_[qt][j][0]*=fac; o_[qt][j][1]*=fac; o_[qt][j][2]*=fac; o_[qt][j][3]*=fac; }
        l_[qt][0]*=fac; l_[qt][1]*=fac; l_[qt][2]*=fac; l_[qt][3]*=fac;
        m_[qt] = mnew;
      }
      float mcur = m_[qt];

      // ---- exp2 + pack + p_lds writes (wave-private slot per q-tile)
      #pragma unroll
      for (int sub=0;sub<4;sub++){
        float e0 = (p[sub][0] == -FINF) ? 0.f : exp2f(p[sub][0] - mcur);
        float e1 = (p[sub][1] == -FINF) ? 0.f : exp2f(p[sub][1] - mcur);
        float e2 = (p[sub][2] == -FINF) ? 0.f : exp2f(p[sub][2] - mcur);
        float e3 = (p[sub][3] == -FINF) ? 0.f : exp2f(p[sub][3] - mcur);
        unsigned u0, u1;
        asm volatile("v_cvt_pk_bf16_f32 %0, %1, %2" : "=v"(u0) : "v"(e0), "v"(e1));
        asm volatile("v_cvt_pk_bf16_f32 %0, %1, %2" : "=v"(u1) : "v"(e2), "v"(e3));
        uint2 w; w.x = u0; w.y = u1;
        int idx = r*64 + ((sub*16 + kq*4) ^ ((r&7)<<3));
        *(uint2*)&p_lds[wave][qt][idx] = w;
      }

      // ---- PV: O^T[d][q] += V^T-frag x P-frag ; l via ones-MFMA
      #pragma unroll
      for (int c=0;c<2;c++){
        bf16x8 pf = *(const bf16x8*)&p_lds[wave][qt][r*64 + ((c*32 + kq*8) ^ ((r&7)<<3))];
        #pragma unroll
        for (int j=0;j<4;j++){
          bf16x8 vf = *(const bf16x8*)&vfr[c][j];
          o_[qt][j] = __builtin_amdgcn_mfma_f32_16x16x32_bf16(vf, pf, o_[qt][j], 0,0,0);
        }
        l_[qt] = __builtin_amdgcn_mfma_f32_16x16x32_bf16(ONES, pf, l_[qt], 0,0,0);
      }
    }
    __syncthreads();   // next K buffer staged (drains gloads) + protects reuse
  }

  #pragma unroll
  for (int qt=0; qt<2; qt++){
    float inv = l_[qt][0] > 0.f ? 1.f/l_[qt][0] : 0.f;
    if (qi[qt] < nq){
      #pragma unroll
      for (int j=0;j<4;j++){
        ushort4 ov = { f2bf(o_[qt][j][0]*inv), f2bf(o_[qt][j][1]*inv),
                       f2bf(o_[qt][j][2]*inv), f2bf(o_[qt][j][3]*inv) };
        *(ushort4*)(Out + (long)z*oBatch + (long)qi[qt]*oRow + h*64 + j*16 + kq*4) = ov;
      }
    }
  }
}

// ---------------------------------------------------------------- LayerNorm rows of 512, f32 in -> bf16 out
__global__ __launch_bounds__(256) void ln_rows(const float* __restrict__ in,
    const float* __restrict__ g, const float* __restrict__ b, u16* __restrict__ out, int rows)
{
  int wave = threadIdx.x >> 6, lane = threadIdx.x & 63;
  int row = blockIdx.x*4 + wave;
  if (row >= rows) return;
  const float4* x = (const float4*)(in + (long)row*512);
  float4 v0 = x[lane], v1 = x[lane+64];
  float s  = v0.x+v0.y+v0.z+v0.w + v1.x+v1.y+v1.z+v1.w;
  float ss = v0.x*v0.x+v0.y*v0.y+v0.z*v0.z+v0.w*v0.w + v1.x*v1.x+v1.y*v1.y+v1.z*v1.z+v1.w*v1.w;
  #pragma unroll
  for (int d=1; d<64; d<<=1){ s += __shfl_xor(s,d); ss += __shfl_xor(ss,d); }
  float mean = s * (1.f/512.f);
  float var = ss * (1.f/512.f) - mean*mean;
  float rs = rsqrtf(var + 1e-5f);
  const float4* gg = (const float4*)g; const float4* bb = (const float4*)b;
  float4 g0 = gg[lane], g1 = gg[lane+64], b0 = bb[lane], b1 = bb[lane+64];
  u16* o = out + (long)row*512;
  ushort4 o0 = { f2bf((v0.x-mean)*rs*g0.x + b0.x), f2bf((v0.y-mean)*rs*g0.y + b0.y),
                 f2bf((v0.z-mean)*rs*g0.z + b0.z), f2bf((v0.w-mean)*rs*g0.w + b0.w) };
  ushort4 o1 = { f2bf((v1.x-mean)*rs*g1.x + b1.x), f2bf((v1.y-mean)*rs*g1.y + b1.y),
                 f2bf((v1.z-mean)*rs*g1.z + b1.z), f2bf((v1.w-mean)*rs*g1.w + b1.w) };
  *(ushort4*)(o + lane*4) = o0;
  *(ushort4*)(o + 256 + lane*4) = o1;
}

// ---------------------------------------------------------------- loc rows: write xn (L2-normalized) and plain bf16 copy
__global__ __launch_bounds__(256) void locprep(const float* __restrict__ y0,
    u16* __restrict__ xn, u16* __restrict__ locb)
{
  int wave = threadIdx.x >> 6, lane = threadIdx.x & 63;
  int rr = blockIdx.x*4 + wave;                 // 0..6271 = b*1568 + t*196 + lp
  int bb = rr/1568, n = rr%1568, tt = n/196, lp = n%196;
  const float4* x = (const float4*)(y0 + ((long)((bb*8+tt)*197) + 1 + lp)*512);
  float4 v0 = x[lane], v1 = x[lane+64];
  float ss = v0.x*v0.x+v0.y*v0.y+v0.z*v0.z+v0.w*v0.w + v1.x*v1.x+v1.y*v1.y+v1.z*v1.z+v1.w*v1.w;
  #pragma unroll
  for (int d=1; d<64; d<<=1) ss += __shfl_xor(ss,d);
  float sc = 1.f / fmaxf(sqrtf(ss), 1e-12f);
  u16* ox = xn + (long)rr*512;
  u16* ol = locb + (long)rr*512;
  ushort4 a0 = { f2bf(v0.x*sc), f2bf(v0.y*sc), f2bf(v0.z*sc), f2bf(v0.w*sc) };
  ushort4 a1 = { f2bf(v1.x*sc), f2bf(v1.y*sc), f2bf(v1.z*sc), f2bf(v1.w*sc) };
  ushort4 c0 = { f2bf(v0.x), f2bf(v0.y), f2bf(v0.z), f2bf(v0.w) };
  ushort4 c1 = { f2bf(v1.x), f2bf(v1.y), f2bf(v1.z), f2bf(v1.w) };
  *(ushort4*)(ox + lane*4) = a0;  *(ushort4*)(ox + 256 + lane*4) = a1;
  *(ushort4*)(ol + lane*4) = c0;  *(ushort4*)(ol + 256 + lane*4) = c1;
}

// ---------------------------------------------------------------- tiny message-path attention S=8,Bt=4,H=8
__global__ __launch_bounds__(64) void msg_attn(const u16* __restrict__ mqkv, u16* __restrict__ matt){
  __shared__ float q_s[8][64], k_s[8][64], v_s[8][64];
  int bh = blockIdx.x; int bt = bh>>3, h = bh&7;
  int lane = threadIdx.x;
  int row = lane>>3, cc = (lane&7)*8;
  #pragma unroll
  for (int e=0;e<8;e++){
    long base = (long)(row*4 + bt)*1536 + h*64 + cc + e;
    q_s[row][cc+e] = bf2f(mqkv[base]);
    k_s[row][cc+e] = bf2f(mqkv[base + 512]);
    v_s[row][cc+e] = bf2f(mqkv[base + 1024]);
  }
  __syncthreads();
  int q = lane>>3, k = lane&7;
  float s = 0.f;
  #pragma unroll 16
  for (int d=0; d<64; d++) s += q_s[q][d]*k_s[k][d];
  s *= 0.125f;
  float mx = s;
  #pragma unroll
  for (int d=1; d<8; d<<=1) mx = fmaxf(mx, __shfl_xor(mx,d));
  float p = __expf(s - mx), ps = p;
  #pragma unroll
  for (int d=1; d<8; d<<=1) ps += __shfl_xor(ps,d);
  p /= ps;
  for (int d=0; d<64; d++){
    float ov = p * v_s[k][d];
    #pragma unroll
    for (int m=1; m<8; m<<=1) ov += __shfl_xor(ov,m);
    if (k == (d>>3)) matt[(long)(q*4 + bt)*512 + h*64 + d] = f2bf(ov);
  }
}

// ---------------------------------------------------------------- small copies / permutes
__global__ __launch_bounds__(256) void gather_glob(const float* __restrict__ y0, float* __restrict__ glob){
  int idx = blockIdx.x*256 + threadIdx.x;      // 16384
  int orow = idx>>9, d = idx&511;
  int tt = orow>>2, bb = orow&3;
  glob[idx] = y0[((long)(bb*8+tt)*197)*512 + d];
}
__global__ __launch_bounds__(256) void copy32(const float* __restrict__ glob, float* __restrict__ y){
  int idx = blockIdx.x*256 + threadIdx.x;
  y[idx] = glob[idx];
}

// ---------------------------------------------------------------- launch
extern "C" void kernel_launch(void* const* d_in, const int* in_sizes, int n_in,
                              void* d_out, int out_size, void* d_ws, size_t ws_size,
                              hipStream_t stream)
{
  const float* x      = (const float*)d_in[0];
  const float* proj_w = (const float*)d_in[1];
  const float* proj_b = (const float*)d_in[2];
  const float* m_ln1g = (const float*)d_in[3];
  const float* m_ln1b = (const float*)d_in[4];
  const float* m_inw  = (const float*)d_in[5];
  const float* m_inb  = (const float*)d_in[6];
  const float* m_outw = (const float*)d_in[7];
  const float* m_outb = (const float*)d_in[8];
  const float* m_ln2g = (const float*)d_in[9];
  const float* m_ln2b = (const float*)d_in[10];
  const float* m_fcw  = (const float*)d_in[11];
  const float* m_fcb  = (const float*)d_in[12];
  const float* m_pw   = (const float*)d_in[13];
  const float* m_pb   = (const float*)d_in[14];
  const float* g_wq = (const float*)d_in[15]; const float* g_bq = (const float*)d_in[16];
  const float* g_wk = (const float*)d_in[17]; const float* g_bk = (const float*)d_in[18];
  const float* g_wv = (const float*)d_in[19]; const float* g_bv = (const float*)d_in[20];
  const float* g_wo = (const float*)d_in[21]; const float* g_bo = (const float*)d_in[22];
  const float* ln1g = (const float*)d_in[23]; const float* ln1b = (const float*)d_in[24];
  const float* a_inw = (const float*)d_in[25]; const float* a_inb = (const float*)d_in[26];
  const float* a_outw = (const float*)d_in[27]; const float* a_outb = (const float*)d_in[28];
  const float* ln2g = (const float*)d_in[29]; const float* ln2b = (const float*)d_in[30];
  const float* fcw = (const float*)d_in[31]; const float* fcb = (const float*)d_in[32];
  const float* pw = (const float*)d_in[33]; const float* pb = (const float*)d_in[34];
  const float* g_mask = (const float*)d_in[35];

  if (ws_size < (size_t)99753984) return;

  char* ws = (char*)d_ws;
  u16* WB = (u16*)ws;
  const long WPROJ=0, WMIN=262144, WMOUT=1048576, WMFC=1310720, WMP=2359296,
             WGQ=3407872, WGK=3670016, WGV=3932160, WGO=4194304,
             WAIN=4456448, WAOUT=5242880, WFC=5505024, WP=6553600;
  float* y0   = (float*)(ws + 15204352);
  float* y    = (float*)(ws + 28114944);
  u16* lnbuf  = (u16*)(ws + 41025536);    // xn / ln outputs [6304][512]; aliases vtg
  u16* vtg    = (u16*)(ws + 41025536);    // masked V^T [4*8*64][1568]
  u16* locb   = (u16*)(ws + 47480832);    // [6272][512]
  u16* qkv    = (u16*)(ws + 53903360);    // [6304][1536]
  u16* xb     = (u16*)(ws + 73269248);    // aliases gm / hbuf / vt2
  u16* gm     = (u16*)(ws + 73269248);    // [4][1568][1568] bf16
  u16* vt2    = (u16*)(ws + 73269248);    // unmasked V^T [32*8*64][256]
  u16* hbuf   = (u16*)(ws + 73269248);    // [6304][2048] bf16
  u16* obuf   = (u16*)(ws + 92938240);    // [6304][512] bf16
  float* glob = (float*)(ws + 99393536);  // [32][512] f32
  u16* mlnb   = (u16*)(ws + 99459072);
  u16* mqkv   = (u16*)(ws + 99491840);
  u16* matt   = (u16*)(ws + 99590144);
  u16* mh     = (u16*)(ws + 99622912);
  float* gbias = (float*)(ws + 99622912); // aliases mh (dead after message blocks)

  // 1. all f32->bf16 conversions (weights + x)
  CvtArgs ca;
  auto setseg=[&](int i, const float* s, u16* d, int n){ ca.src[i]=s; ca.dst[i]=d; ca.n[i]=n; };
  setseg(0,  x,      xb,       6304*512);
  setseg(1,  proj_w, WB+WPROJ, 262144);
  setseg(2,  m_inw,  WB+WMIN,  786432);
  setseg(3,  m_outw, WB+WMOUT, 262144);
  setseg(4,  m_fcw,  WB+WMFC,  1048576);
  setseg(5,  m_pw,   WB+WMP,   1048576);
  setseg(6,  g_wq,   WB+WGQ,   262144);
  setseg(7,  g_wk,   WB+WGK,   262144);
  setseg(8,  g_wv,   WB+WGV,   262144);
  setseg(9,  g_wo,   WB+WGO,   262144);
  setseg(10, a_inw,  WB+WAIN,  786432);
  setseg(11, a_outw, WB+WAOUT, 262144);
  setseg(12, fcw,    WB+WFC,   1048576);
  setseg(13, pw,     WB+WP,    1048576);
  cvt_multi<<<dim3(128,14), 256, 0, stream>>>(ca);

  // 2. x @ proj_w^T + proj_b -> y0 (f32)
  gemm_nt<32,0,4><<<dim3(4,197), 256, 0, stream>>>(xb, WB+WPROJ, proj_b, nullptr, y0, 6304,512,512,512, 0,0,0);

  // 3. global tokens (l==0) -> glob[32][512], rows (t*4+b)
  gather_glob<<<64,256,0,stream>>>(y0, glob);

  // 4. message-passing resblock x2
  for (int it=0; it<2; ++it){
    ln_rows<<<8,256,0,stream>>>(glob, m_ln1g, m_ln1b, mlnb, 32);
    gemm_nt<32,1,4><<<dim3(12,1),256,0,stream>>>(mlnb, WB+WMIN, m_inb, nullptr, mqkv, 32,1536,512,1536, 0,0,0);
    msg_attn<<<32,64,0,stream>>>(mqkv, matt);
    gemm_nt<32,2,4><<<dim3(4,1),256,0,stream>>>(matt, WB+WMOUT, m_outb, glob, glob, 32,512,512,512, 0,0,0);
    ln_rows<<<8,256,0,stream>>>(glob, m_ln2g, m_ln2b, mlnb, 32);
    gemm_nt<32,3,4><<<dim3(16,1),256,0,stream>>>(mlnb, WB+WMFC, m_fcb, nullptr, mh, 32,2048,512,2048, 0,0,0);
    gemm_nt<32,2,4><<<dim3(4,1),256,0,stream>>>(mh, WB+WMP, m_pb, glob, glob, 32,512,2048,512, 0,0,0);
  }

  // 4b. concat graph-attention biases into gbias[1536] (mh region now dead)
  concat_bias<<<6,256,0,stream>>>(g_bq, g_bk, g_bv, gbias);

  // 5. loc rows -> xn (normalized, ->lnbuf) + plain bf16 (->locb)
  locprep<<<1568,256,0,stream>>>(y0, lnbuf, locb);

  // 6. sim = xn@xn^T per batch; gm = relu-thresholded * g_mask (bf16)
  gemm_nt<64,4,3><<<dim3(13,25,4),256,0,stream>>>(lnbuf, lnbuf, nullptr, g_mask, gm,
      1568,1568,512,1568, 1568L*512, 1568L*512, 1568L*1568);

  // 7. graph Q,K,V fused projection -> qkv[6272][1536]  (xn dead after step 6)
  gemm_nt<64,1,3><<<dim3(12,98),256,0,stream>>>(locb, WB+WGQ, gbias, nullptr, qkv, 6272,1536,512,1536, 0,0,0);

  // 7b. V^T for graph attention -> vtg (in dead lnbuf region)
  transpose_v<<<dim3(25,8,4),256,0,stream>>>(qkv, vtg, 1568, 1568L*1536, 1536L, 1024, 1568);

  // 8. masked graph attention -> obuf[6272][512]; heads of a (z,qtile) share an XCD
  //    nqb = 13; groups = 4*13 = 52; blocks = ceil(52/8)*64 = 448
  flash4<true><<<448,256,0,stream>>>(qkv, vtg, gm, obuf,
      1568,1568,13, 1568L*1536, 1536, 1568L*512, 512, 1568L*1568, 1568);

  // 9. out-proj with row permutation directly into y rows 32..6303
  gemm_nt<32,5,4><<<dim3(4,196),256,0,stream>>>(obuf, WB+WGO, g_bo, nullptr, y, 6272,512,512,512, 0,0,0);

  // 10. y rows 0..31 = glob
  copy32<<<64,256,0,stream>>>(glob, y);

  // 11-14. final MHA: y += attn(ln(y))
  ln_rows<<<1576,256,0,stream>>>(y, ln1g, ln1b, lnbuf, 6304);
  gemm_nt<64,1,3><<<dim3(12,99),256,0,stream>>>(lnbuf, WB+WAIN, a_inb, nullptr, qkv, 6304,1536,512,1536, 0,0,0);
  transpose_v<<<dim3(4,8,32),256,0,stream>>>(qkv, vt2, 197, 1536L, 32L*1536, 1024, 256);
  flash4<false><<<dim3(2,8,32),256,0,stream>>>(qkv, vt2, nullptr, obuf,
      197,197,2, 1536, 32L*1536, 512, 32L*512, 0, 256);
  gemm_nt<32,2,4><<<dim3(4,197),256,0,stream>>>(obuf, WB+WAOUT, a_outb, y, y, 6304,512,512,512, 0,0,0);

  // 15-17. MLP: y += qgelu(ln2(y)@fcw^T+fcb)@pw^T+pb ; p-proj fuses out-permute
  ln_rows<<<1576,256,0,stream>>>(y, ln2g, ln2b, lnbuf, 6304);
  gemm_nt<64,3,3><<<dim3(16,99),256,0,stream>>>(lnbuf, WB+WFC, fcb, nullptr, hbuf, 6304,2048,512,2048, 0,0,0);
  gemm_nt<32,6,4><<<dim3(4,197),256,0,stream>>>(hbuf, WB+WP, pb, y, (float*)d_out, 6304,512,2048,512, 0,0,0);
}

// Round 14
// 520.717 us; speedup vs baseline: 1.0282x; 1.0259x over previous
//
#include <hip/hip_runtime.h>
#include <hip/hip_bf16.h>

typedef unsigned short u16;
typedef __attribute__((ext_vector_type(8))) short bf16x8;
typedef __attribute__((ext_vector_type(4))) float f32x4;

#define FINF __builtin_huge_valf()

static __device__ __forceinline__ float bf2f(u16 v){ union{unsigned u; float f;} c; c.u = ((unsigned)v)<<16; return c.f; }
static __device__ __forceinline__ u16 f2bf(float f){ union{__hip_bfloat16 h; u16 u;} c; c.h = __float2bfloat16(f); return c.u; }
static __device__ __forceinline__ bf16x8 scale8(bf16x8 v, float s){
  bf16x8 o;
  #pragma unroll
  for (int e=0;e<8;e++) o[e] = (short)f2bf(bf2f((u16)v[e])*s);
  return o;
}

// async global->LDS, 16B per lane; LDS dest = wave-uniform base + lane*16
static __device__ __forceinline__ void gload16(const void* g, void* l){
  __builtin_amdgcn_global_load_lds(
      (const __attribute__((address_space(1))) void*)g,
      (__attribute__((address_space(3))) void*)l, 16, 0, 0);
}

// raw-barrier pipeline primitives (rule #18)
#define WAIT_VM0()   { asm volatile("s_waitcnt vmcnt(0)" ::: "memory"); __builtin_amdgcn_sched_barrier(0); }
#define BARRIER()    { __builtin_amdgcn_sched_barrier(0); __builtin_amdgcn_s_barrier(); __builtin_amdgcn_sched_barrier(0); }

// ---------------------------------------------------------------- cvt
struct CvtArgs {
  const float* src[14];
  u16* dst[14];
  int n[14];
};
__global__ __launch_bounds__(256) void cvt_multi(CvtArgs a){
  int seg = blockIdx.y;
  const float* s = a.src[seg]; u16* d = a.dst[seg]; int n = a.n[seg];
  for (int i = (blockIdx.x*256 + threadIdx.x)*4; i < n; i += gridDim.x*256*4){
    float4 v = *(const float4*)(s + i);
    ushort4 o = { f2bf(v.x), f2bf(v.y), f2bf(v.z), f2bf(v.w) };
    *(ushort4*)(d + i) = o;
  }
}

__global__ __launch_bounds__(256) void concat_bias(const float* a, const float* b, const float* c, float* o){
  int i = blockIdx.x*256 + threadIdx.x;   // 1536
  o[i] = i < 512 ? a[i] : (i < 1024 ? b[i-512] : c[i-1024]);
}

// ---------------------------------------------------------------- GEMM  C = A @ B^T (+bias, epilogues)
// (round-9 config: 2-buffer, vmcnt(0)+barrier — measured best)
template<int BM, int EPI, int MW>
__global__ __launch_bounds__(256,MW) void gemm_nt(
    const u16* __restrict__ A, const u16* __restrict__ Bw,
    const float* __restrict__ bias, const float* aux, void* out,
    int M, int Nn, int K, int ldc, long aBatch, long bBatch, long cBatch)
{
  constexpr int MI = BM/32;
  constexpr int WSPAN = BM/2;
  __shared__ __align__(16) u16 a_lds[2*BM*64];
  __shared__ __align__(16) u16 b_lds[2*128*64];
  const int z = blockIdx.z;
  const u16* Az = A + (long)z*aBatch;
  const u16* Bz = Bw + (long)z*bBatch;
  const int n0 = blockIdx.x*128, m0 = blockIdx.y*BM;
  const int t = threadIdx.x, lane = t & 63, wave = t >> 6;
  const int wr = wave >> 1, wc = wave & 1;
  const int r = lane & 15, kq = lane >> 4;

  const int srow = t >> 3;                        // 0..31
  const int scol = ((t&7)*8) ^ ((srow&7)<<3);     // swizzled source col (u16)
  int rowA[MI], rowB[4];
  #pragma unroll
  for (int i=0;i<MI;i++){ int ga = m0 + i*32 + srow; rowA[i] = ga < M ? ga : M-1; }
  #pragma unroll
  for (int i=0;i<4;i++){ int gb = n0 + i*32 + srow; rowB[i] = gb < Nn ? gb : Nn-1; }

  f32x4 acc[MI][4] = {};
  const int nkt = K >> 6;

  auto STAGE = [&](int kt, int buf){
    const long koff = (long)kt*64 + scol;
    #pragma unroll
    for (int i=0;i<MI;i++)
      gload16(Az + (long)rowA[i]*K + koff, (char*)a_lds + buf*(BM*128) + i*4096 + wave*1024);
    #pragma unroll
    for (int i=0;i<4;i++)
      gload16(Bz + (long)rowB[i]*K + koff, (char*)b_lds + buf*16384 + i*4096 + wave*1024);
  };

  STAGE(0,0);
  WAIT_VM0(); BARRIER();
  for (int kt=0; kt<nkt; kt++){
    const int cur = kt&1;
    if (kt+1 < nkt) STAGE(kt+1, cur^1);
    const u16* al = a_lds + cur*BM*64;
    const u16* bl = b_lds + cur*8192;
    #pragma unroll
    for (int kk=0; kk<2; kk++){
      bf16x8 af[MI], bfr[4];
      #pragma unroll
      for (int i=0;i<MI;i++){
        int rw = wr*WSPAN + i*16 + r;
        af[i] = *(const bf16x8*)&al[rw*64 + ((kk*32 + kq*8) ^ ((rw&7)<<3))];
      }
      #pragma unroll
      for (int j=0;j<4;j++){
        int rw = wc*64 + j*16 + r;
        bfr[j] = *(const bf16x8*)&bl[rw*64 + ((kk*32 + kq*8) ^ ((rw&7)<<3))];
      }
      #pragma unroll
      for (int i=0;i<MI;i++)
        #pragma unroll
        for (int j=0;j<4;j++)
          acc[i][j] = __builtin_amdgcn_mfma_f32_16x16x32_bf16(af[i], bfr[j], acc[i][j], 0,0,0);
    }
    WAIT_VM0(); BARRIER();
  }

  #pragma unroll
  for (int i=0;i<MI;i++){
    #pragma unroll
    for (int j=0;j<4;j++){
      int gcol = n0 + wc*64 + j*16 + r;
      if (gcol >= Nn) continue;
      float bv = bias ? bias[gcol] : 0.f;
      #pragma unroll
      for (int rr=0; rr<4; rr++){
        int grow = m0 + wr*WSPAN + i*16 + kq*4 + rr;
        if (grow >= M) continue;
        float v = acc[i][j][rr] + bv;
        if constexpr (EPI==0){
          ((float*)out)[(long)z*cBatch + (long)grow*ldc + gcol] = v;
        } else if constexpr (EPI==1){
          ((u16*)out)[(long)z*cBatch + (long)grow*ldc + gcol] = f2bf(v);
        } else if constexpr (EPI==2){
          long idx = (long)z*cBatch + (long)grow*ldc + gcol;
          ((float*)out)[idx] = aux[idx] + v;
        } else if constexpr (EPI==3){
          float g = v / (1.f + __expf(-1.702f*v));
          ((u16*)out)[(long)z*cBatch + (long)grow*ldc + gcol] = f2bf(g);
        } else if constexpr (EPI==4){
          float adj = v < 0.f ? 0.f : v;
          float gmv = aux[(long)grow*Nn + gcol];
          ((u16*)out)[(long)z*cBatch + (long)grow*ldc + gcol] = f2bf(adj*gmv);
        } else if constexpr (EPI==5){
          int b = grow/1568, n = grow%1568, tt = n/196, lp = n%196;
          int yrow = (1+lp)*32 + tt*4 + b;
          ((float*)out)[(long)yrow*ldc + gcol] = v;
        } else if constexpr (EPI==6){
          long idx = (long)grow*ldc + gcol;
          int l = grow>>5, rb = grow&31, tt = rb>>2, bb = rb&3;
          ((float*)out)[((long)((bb*8+tt)*197) + l)*512 + gcol] = aux[idx] + v;
        }
      }
    }
  }
}

// ---------------------------------------------------------------- V transpose
__global__ __launch_bounds__(256) void transpose_v(
    const u16* __restrict__ src, u16* __restrict__ vt,
    int nrows, long zofs, long nofs, int vcol0, int outld)
{
  __shared__ u16 tile[64][66];
  const int t = threadIdx.x;
  const int nt = blockIdx.x, h = blockIdx.y, z = blockIdx.z;
  const int n0 = nt*64;
  const int rlo = t>>3, c0 = (t&7)*8;
  #pragma unroll
  for (int i=0;i<2;i++){
    int nl = i*32 + rlo;
    int n = n0 + nl; int nc = n < nrows ? n : nrows-1;
    const u16* s = src + (long)z*zofs + (long)nc*nofs + vcol0 + h*64 + c0;
    uint4 v = *(const uint4*)s;
    bool dead = n >= nrows;
    #pragma unroll
    for (int e=0;e<8;e++) tile[nl][c0+e] = dead ? (u16)0 : ((const u16*)&v)[e];
  }
  __syncthreads();
  #pragma unroll
  for (int i=0;i<2;i++){
    int d = i*32 + rlo;
    u16 tmp[8];
    #pragma unroll
    for (int e=0;e<8;e++) tmp[e] = tile[c0+e][d];
    int ncol = n0 + c0;
    if (ncol + 8 <= outld){
      u16* dst = vt + ((long)((z*8+h)*64 + d))*outld + ncol;
      *(uint4*)dst = *(uint4*)tmp;
    }
  }
}

// ---------------------------------------------------------------- flash (round-9 best: swapped QK^T, 2 q-tiles/block)
template<bool MASKED>
__global__ __launch_bounds__(256,3) void flash4(
    const u16* __restrict__ QKV, const u16* __restrict__ VT,
    const u16* __restrict__ gmask, u16* __restrict__ Out,
    int nq, int nk, int nqb, long qBatch, long qRow,
    long oBatch, long oRow, long gmBatch, int vtld)
{
  __shared__ __align__(16) u16 k_lds[2*4096];      // [buf][64 key][64 d] swz
  __shared__ __align__(16) u16 p_lds[4][2][1024];  // [wave][qtile][...]
  int h, z, qb;
  if constexpr (MASKED){
    int id = blockIdx.x;
    int a = id>>6, c = id&7; h = (id>>3)&7;
    int G = a*8 + c;
    if (G >= 4*nqb) return;
    z = G / nqb; qb = G % nqb;
  } else {
    qb = blockIdx.x; h = blockIdx.y; z = blockIdx.z;
  }
  const int t = threadIdx.x, lane = t&63, wave = t>>6;
  const int r = lane&15, kq = lane>>4;
  const u16* Qb = QKV + (long)z*qBatch + h*64;
  const u16* Kb = Qb + 512;
  const u16* Vt = VT + (long)(z*8+h)*64*vtld;
  const int qt0 = qb*128;

  int qi[2], qc[2];
  bf16x8 qf[2][2];
  const u16* Gq[2];
  #pragma unroll
  for (int qt=0; qt<2; qt++){
    qi[qt] = qt0 + qt*64 + wave*16 + r;
    qc[qt] = qi[qt] < nq ? qi[qt] : nq-1;
    const u16* qp = Qb + (long)qc[qt]*qRow + kq*8;
    qf[qt][0] = scale8(*(const bf16x8*)qp, 0.125f);
    qf[qt][1] = scale8(*(const bf16x8*)(qp+32), 0.125f);
    Gq[qt] = MASKED ? (gmask + (long)z*gmBatch + (long)qc[qt]*nk) : nullptr;
  }

  const int srow = t>>3;                       // 0..31
  const int scol = ((t&7)*8) ^ ((srow&7)<<3);

  auto stage_k = [&](int kt, int buf){
    #pragma unroll
    for (int i=0;i<2;i++){
      int j = kt*64 + i*32 + srow; if (j > nk-1) j = nk-1;
      gload16(Kb + (long)j*qRow + scol, (char*)k_lds + buf*8192 + i*4096 + wave*1024);
    }
  };

  bf16x8 ONES;
  #pragma unroll
  for (int e=0;e<8;e++) ONES[e] = (short)0x3F80;   // bf16 1.0

  float m_[2] = {-FINF,-FINF};
  f32x4 o_[2][4] = {};  f32x4 l_[2] = {};

  const int nkt = (nk + 63) >> 6;
  stage_k(0,0);
  __syncthreads();
  for (int kt=0; kt<nkt; kt++){
    const int cur = kt&1;
    if (kt+1 < nkt) stage_k(kt+1, cur^1);     // flies during this tile's compute

    // shared V^T fragments, issued early (land under QK^T)
    uint4 vfr[2][4];
    #pragma unroll
    for (int c=0;c<2;c++)
      #pragma unroll
      for (int j=0;j<4;j++)
        vfr[c][j] = *(const uint4*)(Vt + (long)(j*16+r)*vtld + kt*64 + c*32 + kq*8);

    const u16* kl = k_lds + cur*4096;
    #pragma unroll
    for (int qt=0; qt<2; qt++){
      ushort4 gv[4];
      if constexpr (MASKED){
        #pragma unroll
        for (int sub=0;sub<4;sub++)
          gv[sub] = *(const ushort4*)(Gq[qt] + kt*64 + sub*16 + kq*4);
      }

      // ---- QK^T swapped: p[sub][rr], key = kt*64+sub*16+kq*4+rr, col=q(r)
      float p[4][4];
      #pragma unroll
      for (int sub=0; sub<4; sub++){
        int rw = sub*16 + r; int sw = (rw&7)<<3;
        bf16x8 kf0 = *(const bf16x8*)&kl[rw*64 + ((kq*8) ^ sw)];
        bf16x8 kf1 = *(const bf16x8*)&kl[rw*64 + ((32 + kq*8) ^ sw)];
        f32x4 sc = {};
        sc = __builtin_amdgcn_mfma_f32_16x16x32_bf16(kf0, qf[qt][0], sc, 0,0,0);
        sc = __builtin_amdgcn_mfma_f32_16x16x32_bf16(kf1, qf[qt][1], sc, 0,0,0);
        #pragma unroll
        for (int rr=0;rr<4;rr++){
          float sv = sc[rr];
          int key = kt*64 + sub*16 + kq*4 + rr;
          if constexpr (MASKED){
            u16 g = ((const u16*)&gv[sub])[rr];
            sv = (g == 0 || key >= nk) ? -FINF : sv * bf2f(g);
          } else {
            if (key >= nk) sv = -FINF;
          }
          p[sub][rr] = sv;
        }
      }

      // ---- max: in-lane tree over 16, then 2 shfl across kq groups
      float mx;
      { float a0 = fmaxf(fmaxf(p[0][0],p[0][1]), fmaxf(p[0][2],p[0][3]));
        float a1 = fmaxf(fmaxf(p[1][0],p[1][1]), fmaxf(p[1][2],p[1][3]));
        float a2 = fmaxf(fmaxf(p[2][0],p[2][1]), fmaxf(p[2][2],p[2][3]));
        float a3 = fmaxf(fmaxf(p[3][0],p[3][1]), fmaxf(p[3][2],p[3][3]));
        mx = fmaxf(fmaxf(a0,a1), fmaxf(a2,a3)); }
      mx = fmaxf(mx, __shfl_xor(mx, 16));
      mx = fmaxf(mx, __shfl_xor(mx, 32));
      float mnew = fmaxf(m_[qt], mx);
      if (__any(mnew > m_[qt])){               // skip rescale when max unchanged
        float fac = (m_[qt] == -FINF) ? 0.f : __expf(m_[qt] - mnew);
        #pragma unroll
        for (int j=0;j<4;j++){ o_[qt][j][0]*=fac; o_[qt][j][1]*=fac; o_[qt][j][2]*=fac; o_[qt][j][3]*=fac; }
        l_[qt][0]*=fac; l_[qt][1]*=fac; l_[qt][2]*=fac; l_[qt][3]*=fac;
        m_[qt] = mnew;
      }
      mnew = m_[qt];

      // ---- exp + pack + p_lds writes (wave-private slot per q-tile)
      #pragma unroll
      for (int sub=0;sub<4;sub++){
        float e0 = (p[sub][0] == -FINF) ? 0.f : __expf(p[sub][0] - mnew);
        float e1 = (p[sub][1] == -FINF) ? 0.f : __expf(p[sub][1] - mnew);
        float e2 = (p[sub][2] == -FINF) ? 0.f : __expf(p[sub][2] - mnew);
        float e3 = (p[sub][3] == -FINF) ? 0.f : __expf(p[sub][3] - mnew);
        unsigned u0, u1;
        asm volatile("v_cvt_pk_bf16_f32 %0, %1, %2" : "=v"(u0) : "v"(e0), "v"(e1));
        asm volatile("v_cvt_pk_bf16_f32 %0, %1, %2" : "=v"(u1) : "v"(e2), "v"(e3));
        uint2 w; w.x = u0; w.y = u1;
        int idx = r*64 + ((sub*16 + kq*4) ^ ((r&7)<<3));
        *(uint2*)&p_lds[wave][qt][idx] = w;
      }

      // ---- PV: O^T[d][q] += V^T-frag x P-frag ; l via ones-MFMA
      #pragma unroll
      for (int c=0;c<2;c++){
        bf16x8 pf = *(const bf16x8*)&p_lds[wave][qt][r*64 + ((c*32 + kq*8) ^ ((r&7)<<3))];
        #pragma unroll
        for (int j=0;j<4;j++){
          bf16x8 vf = *(const bf16x8*)&vfr[c][j];
          o_[qt][j] = __builtin_amdgcn_mfma_f32_16x16x32_bf16(vf, pf, o_[qt][j], 0,0,0);
        }
        l_[qt] = __builtin_amdgcn_mfma_f32_16x16x32_bf16(ONES, pf, l_[qt], 0,0,0);
      }
    }
    __syncthreads();   // next K buffer staged (drains gloads) + protects reuse
  }

  #pragma unroll
  for (int qt=0; qt<2; qt++){
    float inv = l_[qt][0] > 0.f ? 1.f/l_[qt][0] : 0.f;
    if (qi[qt] < nq){
      #pragma unroll
      for (int j=0;j<4;j++){
        ushort4 ov = { f2bf(o_[qt][j][0]*inv), f2bf(o_[qt][j][1]*inv),
                       f2bf(o_[qt][j][2]*inv), f2bf(o_[qt][j][3]*inv) };
        *(ushort4*)(Out + (long)z*oBatch + (long)qi[qt]*oRow + h*64 + j*16 + kq*4) = ov;
      }
    }
  }
}

// ---------------------------------------------------------------- LayerNorm rows of 512, f32 in -> bf16 out
__global__ __launch_bounds__(256) void ln_rows(const float* __restrict__ in,
    const float* __restrict__ g, const float* __restrict__ b, u16* __restrict__ out, int rows)
{
  int wave = threadIdx.x >> 6, lane = threadIdx.x & 63;
  int row = blockIdx.x*4 + wave;
  if (row >= rows) return;
  const float4* x = (const float4*)(in + (long)row*512);
  float4 v0 = x[lane], v1 = x[lane+64];
  float s  = v0.x+v0.y+v0.z+v0.w + v1.x+v1.y+v1.z+v1.w;
  float ss = v0.x*v0.x+v0.y*v0.y+v0.z*v0.z+v0.w*v0.w + v1.x*v1.x+v1.y*v1.y+v1.z*v1.z+v1.w*v1.w;
  #pragma unroll
  for (int d=1; d<64; d<<=1){ s += __shfl_xor(s,d); ss += __shfl_xor(ss,d); }
  float mean = s * (1.f/512.f);
  float var = ss * (1.f/512.f) - mean*mean;
  float rs = rsqrtf(var + 1e-5f);
  const float4* gg = (const float4*)g; const float4* bb = (const float4*)b;
  float4 g0 = gg[lane], g1 = gg[lane+64], b0 = bb[lane], b1 = bb[lane+64];
  u16* o = out + (long)row*512;
  ushort4 o0 = { f2bf((v0.x-mean)*rs*g0.x + b0.x), f2bf((v0.y-mean)*rs*g0.y + b0.y),
                 f2bf((v0.z-mean)*rs*g0.z + b0.z), f2bf((v0.w-mean)*rs*g0.w + b0.w) };
  ushort4 o1 = { f2bf((v1.x-mean)*rs*g1.x + b1.x), f2bf((v1.y-mean)*rs*g1.y + b1.y),
                 f2bf((v1.z-mean)*rs*g1.z + b1.z), f2bf((v1.w-mean)*rs*g1.w + b1.w) };
  *(ushort4*)(o + lane*4) = o0;
  *(ushort4*)(o + 256 + lane*4) = o1;
}

// ---------------------------------------------------------------- loc rows: write xn (L2-normalized) and plain bf16 copy
__global__ __launch_bounds__(256) void locprep(const float* __restrict__ y0,
    u16* __restrict__ xn, u16* __restrict__ locb)
{
  int wave = threadIdx.x >> 6, lane = threadIdx.x & 63;
  int rr = blockIdx.x*4 + wave;                 // 0..6271 = b*1568 + t*196 + lp
  int bb = rr/1568, n = rr%1568, tt = n/196, lp = n%196;
  const float4* x = (const float4*)(y0 + ((long)((bb*8+tt)*197) + 1 + lp)*512);
  float4 v0 = x[lane], v1 = x[lane+64];
  float ss = v0.x*v0.x+v0.y*v0.y+v0.z*v0.z+v0.w*v0.w + v1.x*v1.x+v1.y*v1.y+v1.z*v1.z+v1.w*v1.w;
  #pragma unroll
  for (int d=1; d<64; d<<=1) ss += __shfl_xor(ss,d);
  float sc = 1.f / fmaxf(sqrtf(ss), 1e-12f);
  u16* ox = xn + (long)rr*512;
  u16* ol = locb + (long)rr*512;
  ushort4 a0 = { f2bf(v0.x*sc), f2bf(v0.y*sc), f2bf(v0.z*sc), f2bf(v0.w*sc) };
  ushort4 a1 = { f2bf(v1.x*sc), f2bf(v1.y*sc), f2bf(v1.z*sc), f2bf(v1.w*sc) };
  ushort4 c0 = { f2bf(v0.x), f2bf(v0.y), f2bf(v0.z), f2bf(v0.w) };
  ushort4 c1 = { f2bf(v1.x), f2bf(v1.y), f2bf(v1.z), f2bf(v1.w) };
  *(ushort4*)(ox + lane*4) = a0;  *(ushort4*)(ox + 256 + lane*4) = a1;
  *(ushort4*)(ol + lane*4) = c0;  *(ushort4*)(ol + 256 + lane*4) = c1;
}

// ---------------------------------------------------------------- tiny message-path attention S=8,Bt=4,H=8
__global__ __launch_bounds__(64) void msg_attn(const u16* __restrict__ mqkv, u16* __restrict__ matt){
  __shared__ float q_s[8][64], k_s[8][64], v_s[8][64];
  int bh = blockIdx.x; int bt = bh>>3, h = bh&7;
  int lane = threadIdx.x;
  int row = lane>>3, cc = (lane&7)*8;
  #pragma unroll
  for (int e=0;e<8;e++){
    long base = (long)(row*4 + bt)*1536 + h*64 + cc + e;
    q_s[row][cc+e] = bf2f(mqkv[base]);
    k_s[row][cc+e] = bf2f(mqkv[base + 512]);
    v_s[row][cc+e] = bf2f(mqkv[base + 1024]);
  }
  __syncthreads();
  int q = lane>>3, k = lane&7;
  float s = 0.f;
  #pragma unroll 16
  for (int d=0; d<64; d++) s += q_s[q][d]*k_s[k][d];
  s *= 0.125f;
  float mx = s;
  #pragma unroll
  for (int d=1; d<8; d<<=1) mx = fmaxf(mx, __shfl_xor(mx,d));
  float p = __expf(s - mx), ps = p;
  #pragma unroll
  for (int d=1; d<8; d<<=1) ps += __shfl_xor(ps,d);
  p /= ps;
  for (int d=0; d<64; d++){
    float ov = p * v_s[k][d];
    #pragma unroll
    for (int m=1; m<8; m<<=1) ov += __shfl_xor(ov,m);
    if (k == (d>>3)) matt[(long)(q*4 + bt)*512 + h*64 + d] = f2bf(ov);
  }
}

// ---------------------------------------------------------------- small copies / permutes
__global__ __launch_bounds__(256) void gather_glob(const float* __restrict__ y0, float* __restrict__ glob){
  int idx = blockIdx.x*256 + threadIdx.x;      // 16384
  int orow = idx>>9, d = idx&511;
  int tt = orow>>2, bb = orow&3;
  glob[idx] = y0[((long)(bb*8+tt)*197)*512 + d];
}
__global__ __launch_bounds__(256) void copy32(const float* __restrict__ glob, float* __restrict__ y){
  int idx = blockIdx.x*256 + threadIdx.x;
  y[idx] = glob[idx];
}

// ---------------------------------------------------------------- launch
extern "C" void kernel_launch(void* const* d_in, const int* in_sizes, int n_in,
                              void* d_out, int out_size, void* d_ws, size_t ws_size,
                              hipStream_t stream)
{
  const float* x      = (const float*)d_in[0];
  const float* proj_w = (const float*)d_in[1];
  const float* proj_b = (const float*)d_in[2];
  const float* m_ln1g = (const float*)d_in[3];
  const float* m_ln1b = (const float*)d_in[4];
  const float* m_inw  = (const float*)d_in[5];
  const float* m_inb  = (const float*)d_in[6];
  const float* m_outw = (const float*)d_in[7];
  const float* m_outb = (const float*)d_in[8];
  const float* m_ln2g = (const float*)d_in[9];
  const float* m_ln2b = (const float*)d_in[10];
  const float* m_fcw  = (const float*)d_in[11];
  const float* m_fcb  = (const float*)d_in[12];
  const float* m_pw   = (const float*)d_in[13];
  const float* m_pb   = (const float*)d_in[14];
  const float* g_wq = (const float*)d_in[15]; const float* g_bq = (const float*)d_in[16];
  const float* g_wk = (const float*)d_in[17]; const float* g_bk = (const float*)d_in[18];
  const float* g_wv = (const float*)d_in[19]; const float* g_bv = (const float*)d_in[20];
  const float* g_wo = (const float*)d_in[21]; const float* g_bo = (const float*)d_in[22];
  const float* ln1g = (const float*)d_in[23]; const float* ln1b = (const float*)d_in[24];
  const float* a_inw = (const float*)d_in[25]; const float* a_inb = (const float*)d_in[26];
  const float* a_outw = (const float*)d_in[27]; const float* a_outb = (const float*)d_in[28];
  const float* ln2g = (const float*)d_in[29]; const float* ln2b = (const float*)d_in[30];
  const float* fcw = (const float*)d_in[31]; const float* fcb = (const float*)d_in[32];
  const float* pw = (const float*)d_in[33]; const float* pb = (const float*)d_in[34];
  const float* g_mask = (const float*)d_in[35];

  if (ws_size < (size_t)99753984) return;

  char* ws = (char*)d_ws;
  u16* WB = (u16*)ws;
  const long WPROJ=0, WMIN=262144, WMOUT=1048576, WMFC=1310720, WMP=2359296,
             WGQ=3407872, WGK=3670016, WGV=3932160, WGO=4194304,
             WAIN=4456448, WAOUT=5242880, WFC=5505024, WP=6553600;
  float* y0   = (float*)(ws + 15204352);
  float* y    = (float*)(ws + 28114944);
  u16* lnbuf  = (u16*)(ws + 41025536);    // xn / ln outputs [6304][512]; aliases vtg
  u16* vtg    = (u16*)(ws + 41025536);    // masked V^T [4*8*64][1568]
  u16* locb   = (u16*)(ws + 47480832);    // [6272][512]
  u16* qkv    = (u16*)(ws + 53903360);    // [6304][1536]
  u16* xb     = (u16*)(ws + 73269248);    // aliases gm / hbuf / vt2
  u16* gm     = (u16*)(ws + 73269248);    // [4][1568][1568] bf16
  u16* vt2    = (u16*)(ws + 73269248);    // unmasked V^T [32*8*64][256]
  u16* hbuf   = (u16*)(ws + 73269248);    // [6304][2048] bf16
  u16* obuf   = (u16*)(ws + 92938240);    // [6304][512] bf16
  float* glob = (float*)(ws + 99393536);  // [32][512] f32
  u16* mlnb   = (u16*)(ws + 99459072);
  u16* mqkv   = (u16*)(ws + 99491840);
  u16* matt   = (u16*)(ws + 99590144);
  u16* mh     = (u16*)(ws + 99622912);
  float* gbias = (float*)(ws + 99622912); // aliases mh (dead after message blocks)

  // 1. all f32->bf16 conversions (weights + x)
  CvtArgs ca;
  auto setseg=[&](int i, const float* s, u16* d, int n){ ca.src[i]=s; ca.dst[i]=d; ca.n[i]=n; };
  setseg(0,  x,      xb,       6304*512);
  setseg(1,  proj_w, WB+WPROJ, 262144);
  setseg(2,  m_inw,  WB+WMIN,  786432);
  setseg(3,  m_outw, WB+WMOUT, 262144);
  setseg(4,  m_fcw,  WB+WMFC,  1048576);
  setseg(5,  m_pw,   WB+WMP,   1048576);
  setseg(6,  g_wq,   WB+WGQ,   262144);
  setseg(7,  g_wk,   WB+WGK,   262144);
  setseg(8,  g_wv,   WB+WGV,   262144);
  setseg(9,  g_wo,   WB+WGO,   262144);
  setseg(10, a_inw,  WB+WAIN,  786432);
  setseg(11, a_outw, WB+WAOUT, 262144);
  setseg(12, fcw,    WB+WFC,   1048576);
  setseg(13, pw,     WB+WP,    1048576);
  cvt_multi<<<dim3(128,14), 256, 0, stream>>>(ca);

  // 2. x @ proj_w^T + proj_b -> y0 (f32)
  gemm_nt<32,0,4><<<dim3(4,197), 256, 0, stream>>>(xb, WB+WPROJ, proj_b, nullptr, y0, 6304,512,512,512, 0,0,0);

  // 3. global tokens (l==0) -> glob[32][512], rows (t*4+b)
  gather_glob<<<64,256,0,stream>>>(y0, glob);

  // 4. message-passing resblock x2
  for (int it=0; it<2; ++it){
    ln_rows<<<8,256,0,stream>>>(glob, m_ln1g, m_ln1b, mlnb, 32);
    gemm_nt<32,1,4><<<dim3(12,1),256,0,stream>>>(mlnb, WB+WMIN, m_inb, nullptr, mqkv, 32,1536,512,1536, 0,0,0);
    msg_attn<<<32,64,0,stream>>>(mqkv, matt);
    gemm_nt<32,2,4><<<dim3(4,1),256,0,stream>>>(matt, WB+WMOUT, m_outb, glob, glob, 32,512,512,512, 0,0,0);
    ln_rows<<<8,256,0,stream>>>(glob, m_ln2g, m_ln2b, mlnb, 32);
    gemm_nt<32,3,4><<<dim3(16,1),256,0,stream>>>(mlnb, WB+WMFC, m_fcb, nullptr, mh, 32,2048,512,2048, 0,0,0);
    gemm_nt<32,2,4><<<dim3(4,1),256,0,stream>>>(mh, WB+WMP, m_pb, glob, glob, 32,512,2048,512, 0,0,0);
  }

  // 4b. concat graph-attention biases into gbias[1536] (mh region now dead)
  concat_bias<<<6,256,0,stream>>>(g_bq, g_bk, g_bv, gbias);

  // 5. loc rows -> xn (normalized, ->lnbuf) + plain bf16 (->locb)
  locprep<<<1568,256,0,stream>>>(y0, lnbuf, locb);

  // 6. sim = xn@xn^T per batch; gm = relu-thresholded * g_mask (bf16)
  gemm_nt<64,4,3><<<dim3(13,25,4),256,0,stream>>>(lnbuf, lnbuf, nullptr, g_mask, gm,
      1568,1568,512,1568, 1568L*512, 1568L*512, 1568L*1568);

  // 7. graph Q,K,V fused projection -> qkv[6272][1536]  (xn dead after step 6)
  gemm_nt<64,1,3><<<dim3(12,98),256,0,stream>>>(locb, WB+WGQ, gbias, nullptr, qkv, 6272,1536,512,1536, 0,0,0);

  // 7b. V^T for graph attention -> vtg (in dead lnbuf region)
  transpose_v<<<dim3(25,8,4),256,0,stream>>>(qkv, vtg, 1568, 1568L*1536, 1536L, 1024, 1568);

  // 8. masked graph attention -> obuf[6272][512]; heads of a (z,qtile) share an XCD
  //    nqb = 13; groups = 4*13 = 52; blocks = ceil(52/8)*64 = 448
  flash4<true><<<448,256,0,stream>>>(qkv, vtg, gm, obuf,
      1568,1568,13, 1568L*1536, 1536, 1568L*512, 512, 1568L*1568, 1568);

  // 9. out-proj with row permutation directly into y rows 32..6303
  gemm_nt<32,5,4><<<dim3(4,196),256,0,stream>>>(obuf, WB+WGO, g_bo, nullptr, y, 6272,512,512,512, 0,0,0);

  // 10. y rows 0..31 = glob
  copy32<<<64,256,0,stream>>>(glob, y);

  // 11-14. final MHA: y += attn(ln(y))
  ln_rows<<<1576,256,0,stream>>>(y, ln1g, ln1b, lnbuf, 6304);
  gemm_nt<64,1,3><<<dim3(12,99),256,0,stream>>>(lnbuf, WB+WAIN, a_inb, nullptr, qkv, 6304,1536,512,1536, 0,0,0);
  transpose_v<<<dim3(4,8,32),256,0,stream>>>(qkv, vt2, 197, 1536L, 32L*1536, 1024, 256);
  flash4<false><<<dim3(2,8,32),256,0,stream>>>(qkv, vt2, nullptr, obuf,
      197,197,2, 1536, 32L*1536, 512, 32L*512, 0, 256);
  gemm_nt<32,2,4><<<dim3(4,197),256,0,stream>>>(obuf, WB+WAOUT, a_outb, y, y, 6304,512,512,512, 0,0,0);

  // 15-17. MLP: y += qgelu(ln2(y)@fcw^T+fcb)@pw^T+pb ; p-proj fuses out-permute
  ln_rows<<<1576,256,0,stream>>>(y, ln2g, ln2b, lnbuf, 6304);
  gemm_nt<64,3,3><<<dim3(16,99),256,0,stream>>>(lnbuf, WB+WFC, fcb, nullptr, hbuf, 6304,2048,512,2048, 0,0,0);
  gemm_nt<32,6,4><<<dim3(4,197),256,0,stream>>>(hbuf, WB+WP, pb, y, (float*)d_out, 6304,512,2048,512, 0,0,0);
}

// Round 15
// 520.465 us; speedup vs baseline: 1.0287x; 1.0005x over previous
//
#include <hip/hip_runtime.h>
#include <hip/hip_bf16.h>

typedef unsigned short u16;
typedef __attribute__((ext_vector_type(8))) short bf16x8;
typedef __attribute__((ext_vector_type(4))) float f32x4;

#define FINF __builtin_huge_valf()

static __device__ __forceinline__ float bf2f(u16 v){ union{unsigned u; float f;} c; c.u = ((unsigned)v)<<16; return c.f; }
static __device__ __forceinline__ u16 f2bf(float f){ union{__hip_bfloat16 h; u16 u;} c; c.h = __float2bfloat16(f); return c.u; }
static __device__ __forceinline__ bf16x8 scale8(bf16x8 v, float s){
  bf16x8 o;
  #pragma unroll
  for (int e=0;e<8;e++) o[e] = (short)f2bf(bf2f((u16)v[e])*s);
  return o;
}

// async global->LDS, 16B per lane; LDS dest = wave-uniform base + lane*16
static __device__ __forceinline__ void gload16(const void* g, void* l){
  __builtin_amdgcn_global_load_lds(
      (const __attribute__((address_space(1))) void*)g,
      (__attribute__((address_space(3))) void*)l, 16, 0, 0);
}

// raw-barrier pipeline primitives (rule #18)
#define WAIT_VM0()   { asm volatile("s_waitcnt vmcnt(0)" ::: "memory"); __builtin_amdgcn_sched_barrier(0); }
#define BARRIER()    { __builtin_amdgcn_sched_barrier(0); __builtin_amdgcn_s_barrier(); __builtin_amdgcn_sched_barrier(0); }

// ---------------------------------------------------------------- cvt
struct CvtArgs {
  const float* src[14];
  u16* dst[14];
  int n[14];
};
__global__ __launch_bounds__(256) void cvt_multi(CvtArgs a){
  int seg = blockIdx.y;
  const float* s = a.src[seg]; u16* d = a.dst[seg]; int n = a.n[seg];
  for (int i = (blockIdx.x*256 + threadIdx.x)*4; i < n; i += gridDim.x*256*4){
    float4 v = *(const float4*)(s + i);
    ushort4 o = { f2bf(v.x), f2bf(v.y), f2bf(v.z), f2bf(v.w) };
    *(ushort4*)(d + i) = o;
  }
}

__global__ __launch_bounds__(256) void concat_bias(const float* a, const float* b, const float* c, float* o){
  int i = blockIdx.x*256 + threadIdx.x;   // 1536
  o[i] = i < 512 ? a[i] : (i < 1024 ? b[i-512] : c[i-1024]);
}

// ---------------------------------------------------------------- GEMM  C = A @ B^T (+bias, epilogues)
// (round-9 config: 2-buffer, vmcnt(0)+barrier — measured best)
template<int BM, int EPI, int MW>
__global__ __launch_bounds__(256,MW) void gemm_nt(
    const u16* __restrict__ A, const u16* __restrict__ Bw,
    const float* __restrict__ bias, const float* aux, void* out,
    int M, int Nn, int K, int ldc, long aBatch, long bBatch, long cBatch)
{
  constexpr int MI = BM/32;
  constexpr int WSPAN = BM/2;
  __shared__ __align__(16) u16 a_lds[2*BM*64];
  __shared__ __align__(16) u16 b_lds[2*128*64];
  const int z = blockIdx.z;
  const u16* Az = A + (long)z*aBatch;
  const u16* Bz = Bw + (long)z*bBatch;
  const int n0 = blockIdx.x*128, m0 = blockIdx.y*BM;
  const int t = threadIdx.x, lane = t & 63, wave = t >> 6;
  const int wr = wave >> 1, wc = wave & 1;
  const int r = lane & 15, kq = lane >> 4;

  const int srow = t >> 3;                        // 0..31
  const int scol = ((t&7)*8) ^ ((srow&7)<<3);     // swizzled source col (u16)
  int rowA[MI], rowB[4];
  #pragma unroll
  for (int i=0;i<MI;i++){ int ga = m0 + i*32 + srow; rowA[i] = ga < M ? ga : M-1; }
  #pragma unroll
  for (int i=0;i<4;i++){ int gb = n0 + i*32 + srow; rowB[i] = gb < Nn ? gb : Nn-1; }

  f32x4 acc[MI][4] = {};
  const int nkt = K >> 6;

  auto STAGE = [&](int kt, int buf){
    const long koff = (long)kt*64 + scol;
    #pragma unroll
    for (int i=0;i<MI;i++)
      gload16(Az + (long)rowA[i]*K + koff, (char*)a_lds + buf*(BM*128) + i*4096 + wave*1024);
    #pragma unroll
    for (int i=0;i<4;i++)
      gload16(Bz + (long)rowB[i]*K + koff, (char*)b_lds + buf*16384 + i*4096 + wave*1024);
  };

  STAGE(0,0);
  WAIT_VM0(); BARRIER();
  for (int kt=0; kt<nkt; kt++){
    const int cur = kt&1;
    if (kt+1 < nkt) STAGE(kt+1, cur^1);
    const u16* al = a_lds + cur*BM*64;
    const u16* bl = b_lds + cur*8192;
    #pragma unroll
    for (int kk=0; kk<2; kk++){
      bf16x8 af[MI], bfr[4];
      #pragma unroll
      for (int i=0;i<MI;i++){
        int rw = wr*WSPAN + i*16 + r;
        af[i] = *(const bf16x8*)&al[rw*64 + ((kk*32 + kq*8) ^ ((rw&7)<<3))];
      }
      #pragma unroll
      for (int j=0;j<4;j++){
        int rw = wc*64 + j*16 + r;
        bfr[j] = *(const bf16x8*)&bl[rw*64 + ((kk*32 + kq*8) ^ ((rw&7)<<3))];
      }
      #pragma unroll
      for (int i=0;i<MI;i++)
        #pragma unroll
        for (int j=0;j<4;j++)
          acc[i][j] = __builtin_amdgcn_mfma_f32_16x16x32_bf16(af[i], bfr[j], acc[i][j], 0,0,0);
    }
    WAIT_VM0(); BARRIER();
  }

  #pragma unroll
  for (int i=0;i<MI;i++){
    #pragma unroll
    for (int j=0;j<4;j++){
      int gcol = n0 + wc*64 + j*16 + r;
      if (gcol >= Nn) continue;
      float bv = bias ? bias[gcol] : 0.f;
      #pragma unroll
      for (int rr=0; rr<4; rr++){
        int grow = m0 + wr*WSPAN + i*16 + kq*4 + rr;
        if (grow >= M) continue;
        float v = acc[i][j][rr] + bv;
        if constexpr (EPI==0){
          ((float*)out)[(long)z*cBatch + (long)grow*ldc + gcol] = v;
        } else if constexpr (EPI==1){
          ((u16*)out)[(long)z*cBatch + (long)grow*ldc + gcol] = f2bf(v);
        } else if constexpr (EPI==2){
          long idx = (long)z*cBatch + (long)grow*ldc + gcol;
          ((float*)out)[idx] = aux[idx] + v;
        } else if constexpr (EPI==3){
          float g = v / (1.f + __expf(-1.702f*v));
          ((u16*)out)[(long)z*cBatch + (long)grow*ldc + gcol] = f2bf(g);
        } else if constexpr (EPI==4){
          float adj = v < 0.f ? 0.f : v;
          float gmv = aux[(long)grow*Nn + gcol];
          ((u16*)out)[(long)z*cBatch + (long)grow*ldc + gcol] = f2bf(adj*gmv);
        } else if constexpr (EPI==5){
          int b = grow/1568, n = grow%1568, tt = n/196, lp = n%196;
          int yrow = (1+lp)*32 + tt*4 + b;
          ((float*)out)[(long)yrow*ldc + gcol] = v;
        } else if constexpr (EPI==6){
          long idx = (long)grow*ldc + gcol;
          int l = grow>>5, rb = grow&31, tt = rb>>2, bb = rb&3;
          ((float*)out)[((long)((bb*8+tt)*197) + l)*512 + gcol] = aux[idx] + v;
        }
      }
    }
  }
}

// ---------------------------------------------------------------- V transpose
__global__ __launch_bounds__(256) void transpose_v(
    const u16* __restrict__ src, u16* __restrict__ vt,
    int nrows, long zofs, long nofs, int vcol0, int outld)
{
  __shared__ u16 tile[64][66];
  const int t = threadIdx.x;
  const int nt = blockIdx.x, h = blockIdx.y, z = blockIdx.z;
  const int n0 = nt*64;
  const int rlo = t>>3, c0 = (t&7)*8;
  #pragma unroll
  for (int i=0;i<2;i++){
    int nl = i*32 + rlo;
    int n = n0 + nl; int nc = n < nrows ? n : nrows-1;
    const u16* s = src + (long)z*zofs + (long)nc*nofs + vcol0 + h*64 + c0;
    uint4 v = *(const uint4*)s;
    bool dead = n >= nrows;
    #pragma unroll
    for (int e=0;e<8;e++) tile[nl][c0+e] = dead ? (u16)0 : ((const u16*)&v)[e];
  }
  __syncthreads();
  #pragma unroll
  for (int i=0;i<2;i++){
    int d = i*32 + rlo;
    u16 tmp[8];
    #pragma unroll
    for (int e=0;e<8;e++) tmp[e] = tile[c0+e][d];
    int ncol = n0 + c0;
    if (ncol + 8 <= outld){
      u16* dst = vt + ((long)((z*8+h)*64 + d))*outld + ncol;
      *(uint4*)dst = *(uint4*)tmp;
    }
  }
}

// ---------------------------------------------------------------- flash (round-9 best: swapped QK^T, 2 q-tiles/block)
template<bool MASKED>
__global__ __launch_bounds__(256,3) void flash4(
    const u16* __restrict__ QKV, const u16* __restrict__ VT,
    const u16* __restrict__ gmask, u16* __restrict__ Out,
    int nq, int nk, int nqb, long qBatch, long qRow,
    long oBatch, long oRow, long gmBatch, int vtld)
{
  __shared__ __align__(16) u16 k_lds[2*4096];      // [buf][64 key][64 d] swz
  __shared__ __align__(16) u16 p_lds[4][2][1024];  // [wave][qtile][...]
  int h, z, qb;
  if constexpr (MASKED){
    int id = blockIdx.x;
    int a = id>>6, c = id&7; h = (id>>3)&7;
    int G = a*8 + c;
    if (G >= 4*nqb) return;
    z = G / nqb; qb = G % nqb;
  } else {
    qb = blockIdx.x; h = blockIdx.y; z = blockIdx.z;
  }
  const int t = threadIdx.x, lane = t&63, wave = t>>6;
  const int r = lane&15, kq = lane>>4;
  const u16* Qb = QKV + (long)z*qBatch + h*64;
  const u16* Kb = Qb + 512;
  const u16* Vt = VT + (long)(z*8+h)*64*vtld;
  const int qt0 = qb*128;

  int qi[2], qc[2];
  bf16x8 qf[2][2];
  const u16* Gq[2];
  #pragma unroll
  for (int qt=0; qt<2; qt++){
    qi[qt] = qt0 + qt*64 + wave*16 + r;
    qc[qt] = qi[qt] < nq ? qi[qt] : nq-1;
    const u16* qp = Qb + (long)qc[qt]*qRow + kq*8;
    qf[qt][0] = scale8(*(const bf16x8*)qp, 0.125f);
    qf[qt][1] = scale8(*(const bf16x8*)(qp+32), 0.125f);
    Gq[qt] = MASKED ? (gmask + (long)z*gmBatch + (long)qc[qt]*nk) : nullptr;
  }

  const int srow = t>>3;                       // 0..31
  const int scol = ((t&7)*8) ^ ((srow&7)<<3);

  auto stage_k = [&](int kt, int buf){
    #pragma unroll
    for (int i=0;i<2;i++){
      int j = kt*64 + i*32 + srow; if (j > nk-1) j = nk-1;
      gload16(Kb + (long)j*qRow + scol, (char*)k_lds + buf*8192 + i*4096 + wave*1024);
    }
  };

  bf16x8 ONES;
  #pragma unroll
  for (int e=0;e<8;e++) ONES[e] = (short)0x3F80;   // bf16 1.0

  float m_[2] = {-FINF,-FINF};
  f32x4 o_[2][4] = {};  f32x4 l_[2] = {};

  const int nkt = (nk + 63) >> 6;
  stage_k(0,0);
  __syncthreads();
  for (int kt=0; kt<nkt; kt++){
    const int cur = kt&1;
    if (kt+1 < nkt) stage_k(kt+1, cur^1);     // flies during this tile's compute

    // shared V^T fragments, issued early (land under QK^T)
    uint4 vfr[2][4];
    #pragma unroll
    for (int c=0;c<2;c++)
      #pragma unroll
      for (int j=0;j<4;j++)
        vfr[c][j] = *(const uint4*)(Vt + (long)(j*16+r)*vtld + kt*64 + c*32 + kq*8);

    const u16* kl = k_lds + cur*4096;
    #pragma unroll
    for (int qt=0; qt<2; qt++){
      ushort4 gv[4];
      if constexpr (MASKED){
        #pragma unroll
        for (int sub=0;sub<4;sub++)
          gv[sub] = *(const ushort4*)(Gq[qt] + kt*64 + sub*16 + kq*4);
      }

      // ---- QK^T swapped: p[sub][rr], key = kt*64+sub*16+kq*4+rr, col=q(r)
      float p[4][4];
      #pragma unroll
      for (int sub=0; sub<4; sub++){
        int rw = sub*16 + r; int sw = (rw&7)<<3;
        bf16x8 kf0 = *(const bf16x8*)&kl[rw*64 + ((kq*8) ^ sw)];
        bf16x8 kf1 = *(const bf16x8*)&kl[rw*64 + ((32 + kq*8) ^ sw)];
        f32x4 sc = {};
        sc = __builtin_amdgcn_mfma_f32_16x16x32_bf16(kf0, qf[qt][0], sc, 0,0,0);
        sc = __builtin_amdgcn_mfma_f32_16x16x32_bf16(kf1, qf[qt][1], sc, 0,0,0);
        #pragma unroll
        for (int rr=0;rr<4;rr++){
          float sv = sc[rr];
          int key = kt*64 + sub*16 + kq*4 + rr;
          if constexpr (MASKED){
            u16 g = ((const u16*)&gv[sub])[rr];
            sv = (g == 0 || key >= nk) ? -FINF : sv * bf2f(g);
          } else {
            if (key >= nk) sv = -FINF;
          }
          p[sub][rr] = sv;
        }
      }

      // ---- max: in-lane tree over 16, then 2 shfl across kq groups
      float mx;
      { float a0 = fmaxf(fmaxf(p[0][0],p[0][1]), fmaxf(p[0][2],p[0][3]));
        float a1 = fmaxf(fmaxf(p[1][0],p[1][1]), fmaxf(p[1][2],p[1][3]));
        float a2 = fmaxf(fmaxf(p[2][0],p[2][1]), fmaxf(p[2][2],p[2][3]));
        float a3 = fmaxf(fmaxf(p[3][0],p[3][1]), fmaxf(p[3][2],p[3][3]));
        mx = fmaxf(fmaxf(a0,a1), fmaxf(a2,a3)); }
      mx = fmaxf(mx, __shfl_xor(mx, 16));
      mx = fmaxf(mx, __shfl_xor(mx, 32));
      float mnew = fmaxf(m_[qt], mx);
      if (__any(mnew > m_[qt])){               // skip rescale when max unchanged
        float fac = (m_[qt] == -FINF) ? 0.f : __expf(m_[qt] - mnew);
        #pragma unroll
        for (int j=0;j<4;j++){ o_[qt][j][0]*=fac; o_[qt][j][1]*=fac; o_[qt][j][2]*=fac; o_[qt][j][3]*=fac; }
        l_[qt][0]*=fac; l_[qt][1]*=fac; l_[qt][2]*=fac; l_[qt][3]*=fac;
        m_[qt] = mnew;
      }
      mnew = m_[qt];

      // ---- exp + pack + p_lds writes (wave-private slot per q-tile)
      #pragma unroll
      for (int sub=0;sub<4;sub++){
        float e0 = (p[sub][0] == -FINF) ? 0.f : __expf(p[sub][0] - mnew);
        float e1 = (p[sub][1] == -FINF) ? 0.f : __expf(p[sub][1] - mnew);
        float e2 = (p[sub][2] == -FINF) ? 0.f : __expf(p[sub][2] - mnew);
        float e3 = (p[sub][3] == -FINF) ? 0.f : __expf(p[sub][3] - mnew);
        unsigned u0, u1;
        asm volatile("v_cvt_pk_bf16_f32 %0, %1, %2" : "=v"(u0) : "v"(e0), "v"(e1));
        asm volatile("v_cvt_pk_bf16_f32 %0, %1, %2" : "=v"(u1) : "v"(e2), "v"(e3));
        uint2 w; w.x = u0; w.y = u1;
        int idx = r*64 + ((sub*16 + kq*4) ^ ((r&7)<<3));
        *(uint2*)&p_lds[wave][qt][idx] = w;
      }

      // ---- PV: O^T[d][q] += V^T-frag x P-frag ; l via ones-MFMA
      #pragma unroll
      for (int c=0;c<2;c++){
        bf16x8 pf = *(const bf16x8*)&p_lds[wave][qt][r*64 + ((c*32 + kq*8) ^ ((r&7)<<3))];
        #pragma unroll
        for (int j=0;j<4;j++){
          bf16x8 vf = *(const bf16x8*)&vfr[c][j];
          o_[qt][j] = __builtin_amdgcn_mfma_f32_16x16x32_bf16(vf, pf, o_[qt][j], 0,0,0);
        }
        l_[qt] = __builtin_amdgcn_mfma_f32_16x16x32_bf16(ONES, pf, l_[qt], 0,0,0);
      }
    }
    __syncthreads();   // next K buffer staged (drains gloads) + protects reuse
  }

  #pragma unroll
  for (int qt=0; qt<2; qt++){
    float inv = l_[qt][0] > 0.f ? 1.f/l_[qt][0] : 0.f;
    if (qi[qt] < nq){
      #pragma unroll
      for (int j=0;j<4;j++){
        ushort4 ov = { f2bf(o_[qt][j][0]*inv), f2bf(o_[qt][j][1]*inv),
                       f2bf(o_[qt][j][2]*inv), f2bf(o_[qt][j][3]*inv) };
        *(ushort4*)(Out + (long)z*oBatch + (long)qi[qt]*oRow + h*64 + j*16 + kq*4) = ov;
      }
    }
  }
}

// ---------------------------------------------------------------- LayerNorm rows of 512, f32 in -> bf16 out
__global__ __launch_bounds__(256) void ln_rows(const float* __restrict__ in,
    const float* __restrict__ g, const float* __restrict__ b, u16* __restrict__ out, int rows)
{
  int wave = threadIdx.x >> 6, lane = threadIdx.x & 63;
  int row = blockIdx.x*4 + wave;
  if (row >= rows) return;
  const float4* x = (const float4*)(in + (long)row*512);
  float4 v0 = x[lane], v1 = x[lane+64];
  float s  = v0.x+v0.y+v0.z+v0.w + v1.x+v1.y+v1.z+v1.w;
  float ss = v0.x*v0.x+v0.y*v0.y+v0.z*v0.z+v0.w*v0.w + v1.x*v1.x+v1.y*v1.y+v1.z*v1.z+v1.w*v1.w;
  #pragma unroll
  for (int d=1; d<64; d<<=1){ s += __shfl_xor(s,d); ss += __shfl_xor(ss,d); }
  float mean = s * (1.f/512.f);
  float var = ss * (1.f/512.f) - mean*mean;
  float rs = rsqrtf(var + 1e-5f);
  const float4* gg = (const float4*)g; const float4* bb = (const float4*)b;
  float4 g0 = gg[lane], g1 = gg[lane+64], b0 = bb[lane], b1 = bb[lane+64];
  u16* o = out + (long)row*512;
  ushort4 o0 = { f2bf((v0.x-mean)*rs*g0.x + b0.x), f2bf((v0.y-mean)*rs*g0.y + b0.y),
                 f2bf((v0.z-mean)*rs*g0.z + b0.z), f2bf((v0.w-mean)*rs*g0.w + b0.w) };
  ushort4 o1 = { f2bf((v1.x-mean)*rs*g1.x + b1.x), f2bf((v1.y-mean)*rs*g1.y + b1.y),
                 f2bf((v1.z-mean)*rs*g1.z + b1.z), f2bf((v1.w-mean)*rs*g1.w + b1.w) };
  *(ushort4*)(o + lane*4) = o0;
  *(ushort4*)(o + 256 + lane*4) = o1;
}

// ---------------------------------------------------------------- loc rows: write xn (L2-normalized) and plain bf16 copy
__global__ __launch_bounds__(256) void locprep(const float* __restrict__ y0,
    u16* __restrict__ xn, u16* __restrict__ locb)
{
  int wave = threadIdx.x >> 6, lane = threadIdx.x & 63;
  int rr = blockIdx.x*4 + wave;                 // 0..6271 = b*1568 + t*196 + lp
  int bb = rr/1568, n = rr%1568, tt = n/196, lp = n%196;
  const float4* x = (const float4*)(y0 + ((long)((bb*8+tt)*197) + 1 + lp)*512);
  float4 v0 = x[lane], v1 = x[lane+64];
  float ss = v0.x*v0.x+v0.y*v0.y+v0.z*v0.z+v0.w*v0.w + v1.x*v1.x+v1.y*v1.y+v1.z*v1.z+v1.w*v1.w;
  #pragma unroll
  for (int d=1; d<64; d<<=1) ss += __shfl_xor(ss,d);
  float sc = 1.f / fmaxf(sqrtf(ss), 1e-12f);
  u16* ox = xn + (long)rr*512;
  u16* ol = locb + (long)rr*512;
  ushort4 a0 = { f2bf(v0.x*sc), f2bf(v0.y*sc), f2bf(v0.z*sc), f2bf(v0.w*sc) };
  ushort4 a1 = { f2bf(v1.x*sc), f2bf(v1.y*sc), f2bf(v1.z*sc), f2bf(v1.w*sc) };
  ushort4 c0 = { f2bf(v0.x), f2bf(v0.y), f2bf(v0.z), f2bf(v0.w) };
  ushort4 c1 = { f2bf(v1.x), f2bf(v1.y), f2bf(v1.z), f2bf(v1.w) };
  *(ushort4*)(ox + lane*4) = a0;  *(ushort4*)(ox + 256 + lane*4) = a1;
  *(ushort4*)(ol + lane*4) = c0;  *(ushort4*)(ol + 256 + lane*4) = c1;
}

// ---------------------------------------------------------------- tiny message-path attention S=8,Bt=4,H=8
__global__ __launch_bounds__(64) void msg_attn(const u16* __restrict__ mqkv, u16* __restrict__ matt){
  __shared__ float q_s[8][64], k_s[8][64], v_s[8][64];
  int bh = blockIdx.x; int bt = bh>>3, h = bh&7;
  int lane = threadIdx.x;
  int row = lane>>3, cc = (lane&7)*8;
  #pragma unroll
  for (int e=0;e<8;e++){
    long base = (long)(row*4 + bt)*1536 + h*64 + cc + e;
    q_s[row][cc+e] = bf2f(mqkv[base]);
    k_s[row][cc+e] = bf2f(mqkv[base + 512]);
    v_s[row][cc+e] = bf2f(mqkv[base + 1024]);
  }
  __syncthreads();
  int q = lane>>3, k = lane&7;
  float s = 0.f;
  #pragma unroll 16
  for (int d=0; d<64; d++) s += q_s[q][d]*k_s[k][d];
  s *= 0.125f;
  float mx = s;
  #pragma unroll
  for (int d=1; d<8; d<<=1) mx = fmaxf(mx, __shfl_xor(mx,d));
  float p = __expf(s - mx), ps = p;
  #pragma unroll
  for (int d=1; d<8; d<<=1) ps += __shfl_xor(ps,d);
  p /= ps;
  for (int d=0; d<64; d++){
    float ov = p * v_s[k][d];
    #pragma unroll
    for (int m=1; m<8; m<<=1) ov += __shfl_xor(ov,m);
    if (k == (d>>3)) matt[(long)(q*4 + bt)*512 + h*64 + d] = f2bf(ov);
  }
}

// ---------------------------------------------------------------- small copies / permutes
__global__ __launch_bounds__(256) void gather_glob(const float* __restrict__ y0, float* __restrict__ glob){
  int idx = blockIdx.x*256 + threadIdx.x;      // 16384
  int orow = idx>>9, d = idx&511;
  int tt = orow>>2, bb = orow&3;
  glob[idx] = y0[((long)(bb*8+tt)*197)*512 + d];
}
__global__ __launch_bounds__(256) void copy32(const float* __restrict__ glob, float* __restrict__ y){
  int idx = blockIdx.x*256 + threadIdx.x;
  y[idx] = glob[idx];
}

// ---------------------------------------------------------------- launch
extern "C" void kernel_launch(void* const* d_in, const int* in_sizes, int n_in,
                              void* d_out, int out_size, void* d_ws, size_t ws_size,
                              hipStream_t stream)
{
  const float* x      = (const float*)d_in[0];
  const float* proj_w = (const float*)d_in[1];
  const float* proj_b = (const float*)d_in[2];
  const float* m_ln1g = (const float*)d_in[3];
  const float* m_ln1b = (const float*)d_in[4];
  const float* m_inw  = (const float*)d_in[5];
  const float* m_inb  = (const float*)d_in[6];
  const float* m_outw = (const float*)d_in[7];
  const float* m_outb = (const float*)d_in[8];
  const float* m_ln2g = (const float*)d_in[9];
  const float* m_ln2b = (const float*)d_in[10];
  const float* m_fcw  = (const float*)d_in[11];
  const float* m_fcb  = (const float*)d_in[12];
  const float* m_pw   = (const float*)d_in[13];
  const float* m_pb   = (const float*)d_in[14];
  const float* g_wq = (const float*)d_in[15]; const float* g_bq = (const float*)d_in[16];
  const float* g_wk = (const float*)d_in[17]; const float* g_bk = (const float*)d_in[18];
  const float* g_wv = (const float*)d_in[19]; const float* g_bv = (const float*)d_in[20];
  const float* g_wo = (const float*)d_in[21]; const float* g_bo = (const float*)d_in[22];
  const float* ln1g = (const float*)d_in[23]; const float* ln1b = (const float*)d_in[24];
  const float* a_inw = (const float*)d_in[25]; const float* a_inb = (const float*)d_in[26];
  const float* a_outw = (const float*)d_in[27]; const float* a_outb = (const float*)d_in[28];
  const float* ln2g = (const float*)d_in[29]; const float* ln2b = (const float*)d_in[30];
  const float* fcw = (const float*)d_in[31]; const float* fcb = (const float*)d_in[32];
  const float* pw = (const float*)d_in[33]; const float* pb = (const float*)d_in[34];
  const float* g_mask = (const float*)d_in[35];

  if (ws_size < (size_t)99753984) return;

  char* ws = (char*)d_ws;
  u16* WB = (u16*)ws;
  const long WPROJ=0, WMIN=262144, WMOUT=1048576, WMFC=1310720, WMP=2359296,
             WGQ=3407872, WGK=3670016, WGV=3932160, WGO=4194304,
             WAIN=4456448, WAOUT=5242880, WFC=5505024, WP=6553600;
  float* y0   = (float*)(ws + 15204352);
  float* y    = (float*)(ws + 28114944);
  u16* lnbuf  = (u16*)(ws + 41025536);    // xn / ln outputs [6304][512]; aliases vtg
  u16* vtg    = (u16*)(ws + 41025536);    // masked V^T [4*8*64][1568]
  u16* locb   = (u16*)(ws + 47480832);    // [6272][512]
  u16* qkv    = (u16*)(ws + 53903360);    // [6304][1536]
  u16* xb     = (u16*)(ws + 73269248);    // aliases gm / hbuf / vt2
  u16* gm     = (u16*)(ws + 73269248);    // [4][1568][1568] bf16
  u16* vt2    = (u16*)(ws + 73269248);    // unmasked V^T [32*8*64][256]
  u16* hbuf   = (u16*)(ws + 73269248);    // [6304][2048] bf16
  u16* obuf   = (u16*)(ws + 92938240);    // [6304][512] bf16
  float* glob = (float*)(ws + 99393536);  // [32][512] f32
  u16* mlnb   = (u16*)(ws + 99459072);
  u16* mqkv   = (u16*)(ws + 99491840);
  u16* matt   = (u16*)(ws + 99590144);
  u16* mh     = (u16*)(ws + 99622912);
  float* gbias = (float*)(ws + 99622912); // aliases mh (dead after message blocks)

  // 1. all f32->bf16 conversions (weights + x)
  CvtArgs ca;
  auto setseg=[&](int i, const float* s, u16* d, int n){ ca.src[i]=s; ca.dst[i]=d; ca.n[i]=n; };
  setseg(0,  x,      xb,       6304*512);
  setseg(1,  proj_w, WB+WPROJ, 262144);
  setseg(2,  m_inw,  WB+WMIN,  786432);
  setseg(3,  m_outw, WB+WMOUT, 262144);
  setseg(4,  m_fcw,  WB+WMFC,  1048576);
  setseg(5,  m_pw,   WB+WMP,   1048576);
  setseg(6,  g_wq,   WB+WGQ,   262144);
  setseg(7,  g_wk,   WB+WGK,   262144);
  setseg(8,  g_wv,   WB+WGV,   262144);
  setseg(9,  g_wo,   WB+WGO,   262144);
  setseg(10, a_inw,  WB+WAIN,  786432);
  setseg(11, a_outw, WB+WAOUT, 262144);
  setseg(12, fcw,    WB+WFC,   1048576);
  setseg(13, pw,     WB+WP,    1048576);
  cvt_multi<<<dim3(128,14), 256, 0, stream>>>(ca);

  // 2. x @ proj_w^T + proj_b -> y0 (f32)
  gemm_nt<32,0,4><<<dim3(4,197), 256, 0, stream>>>(xb, WB+WPROJ, proj_b, nullptr, y0, 6304,512,512,512, 0,0,0);

  // 3. global tokens (l==0) -> glob[32][512], rows (t*4+b)
  gather_glob<<<64,256,0,stream>>>(y0, glob);

  // 4. message-passing resblock x2
  for (int it=0; it<2; ++it){
    ln_rows<<<8,256,0,stream>>>(glob, m_ln1g, m_ln1b, mlnb, 32);
    gemm_nt<32,1,4><<<dim3(12,1),256,0,stream>>>(mlnb, WB+WMIN, m_inb, nullptr, mqkv, 32,1536,512,1536, 0,0,0);
    msg_attn<<<32,64,0,stream>>>(mqkv, matt);
    gemm_nt<32,2,4><<<dim3(4,1),256,0,stream>>>(matt, WB+WMOUT, m_outb, glob, glob, 32,512,512,512, 0,0,0);
    ln_rows<<<8,256,0,stream>>>(glob, m_ln2g, m_ln2b, mlnb, 32);
    gemm_nt<32,3,4><<<dim3(16,1),256,0,stream>>>(mlnb, WB+WMFC, m_fcb, nullptr, mh, 32,2048,512,2048, 0,0,0);
    gemm_nt<32,2,4><<<dim3(4,1),256,0,stream>>>(mh, WB+WMP, m_pb, glob, glob, 32,512,2048,512, 0,0,0);
  }

  // 4b. concat graph-attention biases into gbias[1536] (mh region now dead)
  concat_bias<<<6,256,0,stream>>>(g_bq, g_bk, g_bv, gbias);

  // 5. loc rows -> xn (normalized, ->lnbuf) + plain bf16 (->locb)
  locprep<<<1568,256,0,stream>>>(y0, lnbuf, locb);

  // 6. sim = xn@xn^T per batch; gm = relu-thresholded * g_mask (bf16)
  gemm_nt<64,4,3><<<dim3(13,25,4),256,0,stream>>>(lnbuf, lnbuf, nullptr, g_mask, gm,
      1568,1568,512,1568, 1568L*512, 1568L*512, 1568L*1568);

  // 7. graph Q,K,V fused projection -> qkv[6272][1536]  (xn dead after step 6)
  gemm_nt<64,1,3><<<dim3(12,98),256,0,stream>>>(locb, WB+WGQ, gbias, nullptr, qkv, 6272,1536,512,1536, 0,0,0);

  // 7b. V^T for graph attention -> vtg (in dead lnbuf region)
  transpose_v<<<dim3(25,8,4),256,0,stream>>>(qkv, vtg, 1568, 1568L*1536, 1536L, 1024, 1568);

  // 8. masked graph attention -> obuf[6272][512]; heads of a (z,qtile) share an XCD
  //    nqb = 13; groups = 4*13 = 52; blocks = ceil(52/8)*64 = 448
  flash4<true><<<448,256,0,stream>>>(qkv, vtg, gm, obuf,
      1568,1568,13, 1568L*1536, 1536, 1568L*512, 512, 1568L*1568, 1568);

  // 9. out-proj with row permutation directly into y rows 32..6303
  gemm_nt<32,5,4><<<dim3(4,196),256,0,stream>>>(obuf, WB+WGO, g_bo, nullptr, y, 6272,512,512,512, 0,0,0);

  // 10. y rows 0..31 = glob
  copy32<<<64,256,0,stream>>>(glob, y);

  // 11-14. final MHA: y += attn(ln(y))
  ln_rows<<<1576,256,0,stream>>>(y, ln1g, ln1b, lnbuf, 6304);
  gemm_nt<64,1,3><<<dim3(12,99),256,0,stream>>>(lnbuf, WB+WAIN, a_inb, nullptr, qkv, 6304,1536,512,1536, 0,0,0);
  transpose_v<<<dim3(4,8,32),256,0,stream>>>(qkv, vt2, 197, 1536L, 32L*1536, 1024, 256);
  flash4<false><<<dim3(2,8,32),256,0,stream>>>(qkv, vt2, nullptr, obuf,
      197,197,2, 1536, 32L*1536, 512, 32L*512, 0, 256);
  gemm_nt<32,2,4><<<dim3(4,197),256,0,stream>>>(obuf, WB+WAOUT, a_outb, y, y, 6304,512,512,512, 0,0,0);

  // 15-17. MLP: y += qgelu(ln2(y)@fcw^T+fcb)@pw^T+pb ; p-proj fuses out-permute
  ln_rows<<<1576,256,0,stream>>>(y, ln2g, ln2b, lnbuf, 6304);
  gemm_nt<64,3,3><<<dim3(16,99),256,0,stream>>>(lnbuf, WB+WFC, fcb, nullptr, hbuf, 6304,2048,512,2048, 0,0,0);
  gemm_nt<32,6,4><<<dim3(4,197),256,0,stream>>>(hbuf, WB+WP, pb, y, (float*)d_out, 6304,512,2048,512, 0,0,0);
}